// Round 13
// baseline (566.432 us; speedup 1.0000x reference)
//
#include <hip/hip_runtime.h>
#include <hip/hip_bf16.h>
#include <math.h>

// Problem constants
#define B_  2
#define T_  1024
#define D_  1024
#define H_  16
#define DK_ 64
#define DV_ 128
#define FH_ 2816
#define M_  (B_ * T_)   // 2048 tokens
#define C_  64          // chunk length
#define NCH (T_ / C_)   // 16 chunks

typedef __attribute__((ext_vector_type(8))) short bf16x8;
typedef __attribute__((ext_vector_type(4))) float f32x4;

// ---------------------------------------------------------------------------
// rmsnorm with fp32 and/or bf16 outputs (either may be null)
__global__ __launch_bounds__(256) void rmsnorm_k(
    const float* __restrict__ x, const float* __restrict__ w,
    float* __restrict__ outf, __hip_bfloat16* __restrict__ outb,
    int D, float eps) {
  const int row = blockIdx.x;
  const float* xr = x + (size_t)row * D;
  float ss = 0.f;
  for (int i = threadIdx.x; i < D; i += blockDim.x) { float v = xr[i]; ss += v * v; }
  for (int off = 32; off > 0; off >>= 1) ss += __shfl_xor(ss, off, 64);
  __shared__ float wsum[4];
  __shared__ float s_scale;
  const int lane = threadIdx.x & 63, wid = threadIdx.x >> 6;
  if (lane == 0) wsum[wid] = ss;
  __syncthreads();
  if (threadIdx.x == 0) {
    float tot = 0.f;
    const int nw = blockDim.x >> 6;
    for (int i = 0; i < nw; ++i) tot += wsum[i];
    s_scale = rsqrtf(tot / (float)D + eps);
  }
  __syncthreads();
  const float sc = s_scale;
  for (int i = threadIdx.x; i < D; i += blockDim.x) {
    const float v = xr[i] * sc * w[i];
    if (outf) outf[(size_t)row * D + i] = v;
    if (outb) outb[(size_t)row * D + i] = __float2bfloat16(v);
  }
}

// ---------------------------------------------------------------------------
// Tiled transpose + fp32->bf16 convert: W[K,N] -> Wt[N,K]
__global__ __launch_bounds__(256) void transpose_bf16_k(
    const float* __restrict__ W, __hip_bfloat16* __restrict__ Wt, int K, int N) {
  __shared__ float t[32][33];
  const int k0 = blockIdx.y * 32, n0 = blockIdx.x * 32;
  const int c = threadIdx.x & 31, r = threadIdx.x >> 5;  // r in 0..7
#pragma unroll
  for (int i = 0; i < 4; ++i)
    t[r + 8 * i][c] = W[(size_t)(k0 + r + 8 * i) * N + n0 + c];
  __syncthreads();
#pragma unroll
  for (int i = 0; i < 4; ++i)
    Wt[(size_t)(n0 + r + 8 * i) * K + k0 + c] = __float2bfloat16(t[c][r + 8 * i]);
}

// ---------------------------------------------------------------------------
__device__ __forceinline__ void gload_lds16(const void* g, void* l) {
  __builtin_amdgcn_global_load_lds(
      (const __attribute__((address_space(1))) void*)g,
      (__attribute__((address_space(3))) void*)l, 16, 0, 0);
}

// bf16 MFMA GEMM: C[M,N] = A[M,K] @ Bt[N,K]^T.  Tile BM x BN (64/128 each).
// BK=64 (two linear [BM][32] sub-tiles) + 2-phase double-buffered staging.
// Round-12: widen to 128x128 where grid >= 256 blocks. Audit: at BN=64 each
// wave reads 6 b128 (af4+bf2) per 8 MFMA -> 72cy LDS vs 39cy MFMA = 1.85x
// LDS-read-bound (m134: b128 ~12cy). At 128^2: 8 reads per 16 MFMA (96 vs
// 78cy, near-balanced — the m97 ratio that gave 912 TF vs 343 at 64^2).
// LDS at 128^2/BK=64 dbuf = 64KB -> 2 blocks/CU.
// mode 0: C = acc (fp32); mode 1: C = acc + res (fp32);
// mode 2: Cbf16 = silu(res) * acc   (fused SwiGLU epilogue)
template<int BM, int BN>
__global__ __launch_bounds__(256) void mfma_gemm_k(
    const __hip_bfloat16* __restrict__ A, const __hip_bfloat16* __restrict__ Bt,
    const float* __restrict__ res, void* __restrict__ Cout,
    int M, int N, int K, int mode) {
  __shared__ __hip_bfloat16 As[2][BM * 64];   // two [BM][32] sub-tiles each
  __shared__ __hip_bfloat16 Bs[2][BN * 64];
  constexpr int MF = BM / 32;        // a-frags per wave (4 or 2)
  constexpr int NF = BN / 32;        // b-frags per wave (4 or 2)
  const int tid = threadIdx.x;
  const int lane = tid & 63;
  const int wv = tid >> 6;
  const int wm = (wv >> 1) * (BM / 2), wn = (wv & 1) * (BN / 2);
  const int bm = blockIdx.y * BM, bn = blockIdx.x * BN;
  const int l15 = lane & 15, lq8 = (lane >> 4) * 8;
  const int ar = tid >> 2;
  const int ac = (tid & 3) * 8;
  const size_t Abase = (size_t)(bm + ar) * K + ac;
  const size_t Bbase = (size_t)(bn + ar) * K + ac;
  f32x4 acc[MF][NF];
#pragma unroll
  for (int i = 0; i < MF; ++i)
#pragma unroll
    for (int j = 0; j < NF; ++j) acc[i][j] = (f32x4){0.f, 0.f, 0.f, 0.f};

  // stage 64-wide k-slab [k0,k0+64) into buffer buf as two linear sub-tiles
  auto stage = [&](int buf, int k0) {
#pragma unroll
    for (int s = 0; s < 2; ++s) {
      const int kk = k0 + 32 * s;
      char* dA = (char*)&As[buf][s * BM * 32] + tid * 16;
      gload_lds16(A + Abase + kk, dA);
      if constexpr (BM == 128)
        gload_lds16(A + Abase + (size_t)64 * K + kk, dA + 4096);
      char* dB = (char*)&Bs[buf][s * BN * 32] + tid * 16;
      gload_lds16(Bt + Bbase + kk, dB);
      if constexpr (BN == 128)
        gload_lds16(Bt + Bbase + (size_t)64 * K + kk, dB + 4096);
    }
  };

  stage(0, 0);
  __syncthreads();                 // implicit vmcnt(0): buf0 ready
  int cur = 0;
#pragma unroll 2
  for (int k0 = 0; k0 < K; k0 += 64) {
    if (k0 + 64 < K) stage(cur ^ 1, k0 + 64);   // in flight during compute
#pragma unroll
    for (int s = 0; s < 2; ++s) {
      bf16x8 af[MF], bfr[NF];
#pragma unroll
      for (int i = 0; i < MF; ++i)
        af[i] = *(const bf16x8*)(&As[cur][s * BM * 32] + (wm + i * 16 + l15) * 32 + lq8);
#pragma unroll
      for (int j = 0; j < NF; ++j)
        bfr[j] = *(const bf16x8*)(&Bs[cur][s * BN * 32] + (wn + j * 16 + l15) * 32 + lq8);
#pragma unroll
      for (int i = 0; i < MF; ++i)
#pragma unroll
        for (int j = 0; j < NF; ++j)
          acc[i][j] = __builtin_amdgcn_mfma_f32_16x16x32_bf16(af[i], bfr[j], acc[i][j], 0, 0, 0);
    }
    __syncthreads();               // drains the k0+64 glds AFTER compute
    cur ^= 1;
  }
  const int r0 = (lane >> 4) * 4;
#pragma unroll
  for (int i = 0; i < MF; ++i) {
#pragma unroll
    for (int j = 0; j < NF; ++j) {
      const int row = bm + wm + i * 16 + r0;
      const int col = bn + wn + j * 16 + l15;
#pragma unroll
      for (int r = 0; r < 4; ++r) {
        const size_t idx = (size_t)(row + r) * N + col;
        const float a = acc[i][j][r];
        if (mode == 0) ((float*)Cout)[idx] = a;
        else if (mode == 1) ((float*)Cout)[idx] = a + res[idx];
        else {
          const float s = res[idx];
          ((__hip_bfloat16*)Cout)[idx] =
              __float2bfloat16(s * (1.f / (1.f + __expf(-s))) * a);
        }
      }
    }
  }
}

// ---------------------------------------------------------------------------
// pa/pb = h @ [Wa|Wb] — all 256 threads active (8-way K-split + reduce).
__global__ __launch_bounds__(256) void skinny_k(
    const float* __restrict__ h, const float* __restrict__ Wa,
    const float* __restrict__ Wb, float* __restrict__ pa,
    float* __restrict__ pb, int K) {
  __shared__ float hl[D_];
  __shared__ float red[8][32];
  const int row = blockIdx.x;
  const int tid = threadIdx.x;
  {
    const float4* src = (const float4*)(h + (size_t)row * K);
    ((float4*)hl)[tid] = src[tid];
  }
  __syncthreads();
  const int col = tid & 31, sub = tid >> 5;
  const float* W = (col < 16) ? Wa : Wb;
  const int cc = col & 15;
  float s = 0.f;
  const int kk0 = sub * 128;
  for (int k = kk0; k < kk0 + 128; ++k) s += hl[k] * W[k * H_ + cc];
  red[sub][col] = s;
  __syncthreads();
  if (tid < 32) {
    float t = 0.f;
#pragma unroll
    for (int i = 0; i < 8; ++i) t += red[i][tid];
    if (tid < 16) pa[(size_t)row * H_ + tid] = t;
    else          pb[(size_t)row * H_ + tid - 16] = t;
  }
}

// ---------------------------------------------------------------------------
// causal depthwise conv + silu. Row stride / column offset parametrized so
// merged projection buffers ([M][4096] q|k|v) can be consumed in place.
__global__ __launch_bounds__(256) void conv_silu_k(
    const float* __restrict__ src, const float* __restrict__ w,
    float* __restrict__ dst, int C, int sstr, int soff) {
  const int bt = blockIdx.x;
  const int b = bt / T_, t = bt % T_;
  const float* s = src + (size_t)b * T_ * sstr + soff;
  for (int c = threadIdx.x; c < C; c += blockDim.x) {
    const float w0 = w[c * 4 + 0], w1 = w[c * 4 + 1],
                w2 = w[c * 4 + 2], w3 = w[c * 4 + 3];
    float acc = s[(size_t)t * sstr + c] * w3;
    if (t >= 1) acc += s[(size_t)(t - 1) * sstr + c] * w2;
    if (t >= 2) acc += s[(size_t)(t - 2) * sstr + c] * w1;
    if (t >= 3) acc += s[(size_t)(t - 3) * sstr + c] * w0;
    dst[(size_t)bt * C + c] = acc * (1.f / (1.f + __expf(-acc)));
  }
}

// ---------------------------------------------------------------------------
__global__ void beta_g_k(const float* __restrict__ pa, const float* __restrict__ pb,
                         const float* __restrict__ dtb, const float* __restrict__ Alog,
                         float* __restrict__ g, float* __restrict__ beta, int n) {
  const int i = blockIdx.x * blockDim.x + threadIdx.x;
  if (i >= n) return;
  const int h = i & (H_ - 1);
  const float xx = pa[i] + dtb[h];
  const float sp = (xx > 20.f) ? xx : log1pf(expf(xx));
  g[i] = -expf(Alog[h]) * sp;
  beta[i] = 1.f / (1.f + expf(-pb[i]));
}

// ---------------------------------------------------------------------------
__global__ __launch_bounds__(64) void l2norm_k(float* __restrict__ q, float scale) {
  const size_t row = blockIdx.x;
  const int lane = threadIdx.x;
  const float v = q[row * 64 + lane];
  float ss = v * v;
  for (int off = 32; off > 0; off >>= 1) ss += __shfl_xor(ss, off, 64);
  q[row * 64 + lane] = v * rsqrtf(ss + 1e-6f) * scale;
}

// ---------------------------------------------------------------------------
// Chunked gated delta rule, phase A. Barrier-free solve (round 8).
__global__ __launch_bounds__(256) void chunk_prep_k(
    const float* __restrict__ q, float* __restrict__ k, float* __restrict__ v,
    const float* __restrict__ g, const float* __restrict__ beta,
    float* __restrict__ qkd, float* __restrict__ kdt, float* __restrict__ gam,
    float* __restrict__ wt) {
  const int task = blockIdx.x;
  const int bh = task >> 4, n = task & (NCH - 1);
  const int b = bh >> 4, h = bh & 15;
  const int t0 = n * C_;
  const int tid = threadIdx.x;
  __shared__ float lk[C_][68];     // staged k rows
  __shared__ float Gs[C_][68];     // strict-lower β-folded Gram (zeros above)
  __shared__ float Xs[C_][100];    // 96-column RHS/solution panel
  __shared__ float Td[4][16][17];  // 16x16 diagonal-block inverses
  __shared__ float lb[C_], lgam[C_], lbeta[C_], lbg[C_];
  // stage k chunk
  {
    const int r = tid >> 2, cq = (tid & 3) * 16;
    const float* src = k + (((size_t)b * T_ + t0 + r) * H_ + h) * DK_ + cq;
#pragma unroll
    for (int i = 0; i < 4; ++i)
      *(float4*)&lk[r][cq + 4 * i] = ((const float4*)src)[i];
  }
  // g cumsum (wave 0), γ, β, βγ
  if (tid < 64) {
    const size_t gi = ((size_t)b * T_ + t0 + tid) * H_ + h;
    float xx = g[gi];
    const float bb = beta[gi];
    lbeta[tid] = bb;
#pragma unroll
    for (int off = 1; off < 64; off <<= 1) {
      float y = __shfl_up(xx, off, 64);
      if (tid >= off) xx += y;
    }
    lb[tid] = xx;
    const float gm = __expf(xx);
    lgam[tid] = gm;
    lbg[tid] = bb * gm;
  }
  __syncthreads();
  const int r4g = (tid >> 4) * 4;
  const int sl = tid & 15;
  // Gram: G = β-folded strict-lower K K^T decay; QKd = (Q K^T) decay
  {
    const float* qg = q + (((size_t)b * T_ + t0) * H_ + h) * DK_;
    float accA[4][4] = {};
    float accQ[4][4] = {};
    for (int d = 0; d < 64; d += 4) {
      float4 kt[4], ks[4], qt[4];
#pragma unroll
      for (int i = 0; i < 4; ++i) kt[i] = *(const float4*)&lk[r4g + i][d];
#pragma unroll
      for (int j = 0; j < 4; ++j) ks[j] = *(const float4*)&lk[sl + 16 * j][d];
#pragma unroll
      for (int i = 0; i < 4; ++i) qt[i] = *(const float4*)(qg + (size_t)(r4g + i) * (H_ * DK_) + d);
#pragma unroll
      for (int i = 0; i < 4; ++i)
#pragma unroll
        for (int j = 0; j < 4; ++j) {
          accA[i][j] += kt[i].x * ks[j].x + kt[i].y * ks[j].y + kt[i].z * ks[j].z + kt[i].w * ks[j].w;
          accQ[i][j] += qt[i].x * ks[j].x + qt[i].y * ks[j].y + qt[i].z * ks[j].z + qt[i].w * ks[j].w;
        }
    }
    float* qo = qkd + (size_t)task * 4096;
#pragma unroll
    for (int i = 0; i < 4; ++i)
#pragma unroll
      for (int j = 0; j < 4; ++j) {
        const int t = r4g + i, s = sl + 16 * j;
        const float dec = (s <= t) ? __expf(lb[t] - lb[s]) : 0.f;
        Gs[t][s] = (t > s) ? lbeta[t] * accA[i][j] * dec : 0.f;
        qo[t * 64 + s] = accQ[i][j] * dec;
      }
  }
  // kdtT[s][dk] = k[s][dk] * exp(bC - lb[s])  (coalesced rows, 1 exp/thread)
  {
    const int s = tid >> 2, dq = (tid & 3) * 16;
    const float e = __expf(lb[63] - lb[s]);
    float* dst = kdt + (size_t)task * 4096 + s * 64 + dq;
#pragma unroll
    for (int m = 0; m < 4; ++m) {
      float4 kv = *(const float4*)&lk[s][dq + 4 * m];
      kv.x *= e; kv.y *= e; kv.z *= e; kv.w *= e;
      *(float4*)(dst + 4 * m) = kv;
    }
  }
  if (tid < 64) gam[(size_t)task * 64 + tid] = lgam[tid];
  __syncthreads();
  // Td (threads 0..63: 4 blocks x 16 columns, registers only) + RHS0 load
  if (tid < 64) {
    const int blk = tid >> 4, cI = tid & 15;
    float Xc[16];
#pragma unroll
    for (int t = 0; t < 16; ++t) Xc[t] = (t == cI) ? 1.f : 0.f;
#pragma unroll
    for (int t = 1; t < 16; ++t) {
      float acc = 0.f;
#pragma unroll
      for (int s = 0; s < t; ++s)
        acc += Gs[blk * 16 + t][blk * 16 + s] * Xc[s];
      Xc[t] -= acc;
    }
#pragma unroll
    for (int t = 0; t < 16; ++t) Td[blk][t][cI] = Xc[t];
  } else {
    // RHS half 0: βV columns 0..95 (192 threads, 32 cells each)
    for (int idx = tid - 64; idx < 64 * 96; idx += 192) {
      const int t = idx / 96, c = idx % 96;
      Xs[t][c] = lbeta[t] * v[(((size_t)b * T_ + t0 + t) * H_ + h) * DV_ + c];
    }
  }
  __syncthreads();
  const int rt = tid & 15;          // row within block
  const int cg = tid >> 4;          // column group: cols cg*6 .. cg*6+5
#pragma unroll 1
  for (int half = 0; half < 2; ++half) {
    // 4-stage blocked sweep — BARRIER-FREE (quarter-wave column ownership;
    // same-wave LDS forwarding)
#pragma unroll
    for (int bi = 0; bi < 4; ++bi) {
      if (bi > 0) {
        float acc[6] = {0.f, 0.f, 0.f, 0.f, 0.f, 0.f};
        for (int kk = 0; kk < 16 * bi; ++kk) {
          const float gvv = Gs[16 * bi + rt][kk];
#pragma unroll
          for (int c = 0; c < 6; ++c) acc[c] += gvv * Xs[kk][cg * 6 + c];
        }
#pragma unroll
        for (int c = 0; c < 6; ++c) Xs[16 * bi + rt][cg * 6 + c] -= acc[c];
      }
      float y[6] = {0.f, 0.f, 0.f, 0.f, 0.f, 0.f};
#pragma unroll
      for (int s = 0; s < 16; ++s) {
        const float tv = Td[bi][rt][s];
#pragma unroll
        for (int c = 0; c < 6; ++c) y[c] += tv * Xs[16 * bi + s][cg * 6 + c];
      }
#pragma unroll
      for (int c = 0; c < 6; ++c) Xs[16 * bi + rt][cg * 6 + c] = y[c];
    }
    __syncthreads();   // solve complete -> all-thread writeback
    // writeback + next RHS
    if (half == 0) {
      for (int idx = tid; idx < 64 * 96; idx += 256) {
        const int t = idx / 96, c = idx % 96;
        v[(((size_t)b * T_ + t0 + t) * H_ + h) * DV_ + c] = Xs[t][c];
      }
      __syncthreads();   // writeback reads done before RHS overwrite
      // RHS half 1: cols 0..31 = βV cols 96..127; cols 32..95 = βγ·K cols 0..63
      for (int idx = tid; idx < 64 * 96; idx += 256) {
        const int t = idx / 96, c = idx % 96;
        if (c < 32)
          Xs[t][c] = lbeta[t] * v[(((size_t)b * T_ + t0 + t) * H_ + h) * DV_ + 96 + c];
        else
          Xs[t][c] = lbg[t] * lk[t][c - 32];
      }
      __syncthreads();   // RHS visible to solver quarter-waves
    } else {
      // v cols 96..127
      for (int idx = tid; idx < 64 * 32; idx += 256) {
        const int t = idx >> 5, cc = idx & 31;
        v[(((size_t)b * T_ + t0 + t) * H_ + h) * DV_ + 96 + cc] = Xs[t][cc];
      }
      // wt[task][dk][t] = Xs[t][32+dk]  (transposed W; coalesced per-thread rows)
      {
        const int dk = tid & 63, tg = tid >> 6;
        float buf[16];
#pragma unroll
        for (int j = 0; j < 16; ++j) buf[j] = Xs[16 * tg + j][32 + dk];
        float* dst = wt + (size_t)task * 4096 + dk * 64 + 16 * tg;
#pragma unroll
        for (int m = 0; m < 4; ++m)
          *(float4*)(dst + 4 * m) =
              make_float4(buf[4 * m], buf[4 * m + 1], buf[4 * m + 2], buf[4 * m + 3]);
      }
    }
  }
}

// ---------------------------------------------------------------------------
// Serial recurrence — round-9 256-thread version (best measured: 46.6us).
__global__ __launch_bounds__(256) void chunk_rec_k(
    const float* __restrict__ WT, float* __restrict__ u,
    const float* __restrict__ kdtT, const float* __restrict__ gam,
    float* __restrict__ Sst) {
  const int bh = blockIdx.x & 31, cg = blockIdx.x >> 5;   // XCD swizzle kept
  const int b = bh >> 4, h = bh & 15;
  const int c0 = cg * 16;
  const int tid = threadIdx.x;
  const int w = tid >> 6;             // wave 0..3
  const int lane = tid & 63;
  const int L15 = lane & 15;
  const int t4 = L15 * 4;             // 4 rows (tokens in mm1 / dk in mm2)
  const int c = w * 4 + (lane >> 4);  // owned column (0..15)
  const int iot = tid >> 2;           // I/O ownership: row 0..63
  const int ioq = (tid & 3) * 4;      // I/O col quad base

  __shared__ float Wt[2][64 * 64];    // [buf][dk*64+token]  (linear, glds dest)
  __shared__ float Kt[2][64 * 64];    // [buf][s*64+dk]
  __shared__ float SsT[16][68];       // S^T [col][dk]
  __shared__ float UbT[16][68];       // U^T [col][s]
  __shared__ float Ub0[64][17];       // staged u [t][col]

  float Sr[4];
#pragma unroll
  for (int i = 0; i < 4; ++i) Sr[i] = 0.f;
#pragma unroll
  for (int i = 0; i < 4; ++i) SsT[c][t4 + i] = 0.f;

  // prologue: glds chunk 0 into buffer 0 (each wave stages its row quarter)
  {
    const float* sW = WT + (size_t)(bh * NCH) * 4096 + w * 1024 + lane * 4;
    const float* sK = kdtT + (size_t)(bh * NCH) * 4096 + w * 1024 + lane * 4;
    char* lW = (char*)&Wt[0][w * 1024] + lane * 16;
    char* lK = (char*)&Kt[0][w * 1024] + lane * 16;
#pragma unroll
    for (int i = 0; i < 4; ++i) {
      gload_lds16(sW + i * 256, lW + i * 1024);
      gload_lds16(sK + i * 256, lK + i * 1024);
    }
  }
  __syncthreads();

#pragma unroll 1
  for (int n = 0; n < NCH; ++n) {
    const int cur = n & 1, nx = cur ^ 1;
    const int task = bh * NCH + n;
    const int t0 = n * C_;
    const int n1 = (n + 1 < NCH) ? n + 1 : NCH - 1;   // clamped (no branch BB)
    const int task1 = bh * NCH + n1;
    const float gC = gam[(size_t)task * 64 + 63];

    // A1: issue coalesced u load FIRST (its wait then leaves glds in flight)
    const float4 uv = *(const float4*)(
        u + (((size_t)b * T_ + t0 + iot) * H_ + h) * DV_ + c0 + ioq);
    // A2: issue next-chunk glds staging (drained at bar1; hidden under mm1)
    {
      const float* sW = WT + (size_t)task1 * 4096 + w * 1024 + lane * 4;
      const float* sK = kdtT + (size_t)task1 * 4096 + w * 1024 + lane * 4;
      char* lW = (char*)&Wt[nx][w * 1024] + lane * 16;
      char* lK = (char*)&Kt[nx][w * 1024] + lane * 16;
#pragma unroll
      for (int i = 0; i < 4; ++i) {
        gload_lds16(sW + i * 256, lW + i * 1024);
        gload_lds16(sK + i * 256, lK + i * 1024);
      }
    }
    __builtin_amdgcn_sched_barrier(0);
    // A3: Sst writeback (pre-chunk state, coalesced; reads SsT cross-wave,
    //     ordered by prior bar2 / init)
    {
      float4 sv;
      sv.x = SsT[ioq + 0][iot]; sv.y = SsT[ioq + 1][iot];
      sv.z = SsT[ioq + 2][iot]; sv.w = SsT[ioq + 3][iot];
      *(float4*)(Sst + (size_t)task * 8192 + iot * 128 + c0 + ioq) = sv;
    }
    // A4: mm1: acc[i] = sum_k W[t4+i][k] * S[k][c]
    float4 srow[16];
#pragma unroll
    for (int g = 0; g < 16; ++g) srow[g] = *(const float4*)&SsT[c][4 * g];
    float acc[4] = {0.f, 0.f, 0.f, 0.f};
#pragma unroll
    for (int g = 0; g < 16; ++g) {
      const float sj[4] = {srow[g].x, srow[g].y, srow[g].z, srow[g].w};
#pragma unroll
      for (int j = 0; j < 4; ++j) {
        const float4 wv = *(const float4*)&Wt[cur][(4 * g + j) * 64 + t4];
        acc[0] += wv.x * sj[j]; acc[1] += wv.y * sj[j];
        acc[2] += wv.z * sj[j]; acc[3] += wv.w * sj[j];
      }
    }
    // A5: commit staged u -> Ub0 (vmcnt wait covered by mm1)
    Ub0[iot][ioq + 0] = uv.x; Ub0[iot][ioq + 1] = uv.y;
    Ub0[iot][ioq + 2] = uv.z; Ub0[iot][ioq + 3] = uv.w;
    __syncthreads();  // bar1: Ub0 visible; glds for [nx] drained

    // B1: U-form (reads Ub0 cross-wave; writes UbT same-wave rows)
#pragma unroll
    for (int i = 0; i < 4; ++i)
      UbT[c][t4 + i] = Ub0[t4 + i][c] - acc[i];
    // B2: mm2: acc2[i] = sum_s K̂[s][t4+i] * U[s][c]  (same-wave UbT row)
    float4 urow[16];
#pragma unroll
    for (int g = 0; g < 16; ++g) urow[g] = *(const float4*)&UbT[c][4 * g];
    float ac2[4] = {0.f, 0.f, 0.f, 0.f};
#pragma unroll
    for (int g = 0; g < 16; ++g) {
      const float uj[4] = {urow[g].x, urow[g].y, urow[g].z, urow[g].w};
#pragma unroll
      for (int j = 0; j < 4; ++j) {
        const float4 kv = *(const float4*)&Kt[cur][(4 * g + j) * 64 + t4];
        ac2[0] += kv.x * uj[j]; ac2[1] += kv.y * uj[j];
        ac2[2] += kv.z * uj[j]; ac2[3] += kv.w * uj[j];
      }
    }
    // B3: state update + SsT write (same-wave rows)
#pragma unroll
    for (int i = 0; i < 4; ++i) {
      Sr[i] = gC * Sr[i] + ac2[i];
      SsT[c][t4 + i] = Sr[i];
    }
    __syncthreads();  // bar2: UbT/SsT complete

    // C: coalesced u writeback from UbT (cross-wave, ordered by bar2)
    {
      float4 ov;
      ov.x = UbT[ioq + 0][iot]; ov.y = UbT[ioq + 1][iot];
      ov.z = UbT[ioq + 2][iot]; ov.w = UbT[ioq + 3][iot];
      *(float4*)(u + (((size_t)b * T_ + t0 + iot) * H_ + h) * DV_ + c0 + ioq) = ov;
    }
  }
}

// ---------------------------------------------------------------------------
// Parallel O with fused gatenorm (unchanged).
__global__ __launch_bounds__(128) void chunk_o_k(
    const float* __restrict__ q, const float* __restrict__ qkd,
    const float* __restrict__ ub, const float* __restrict__ Sst,
    const float* __restrict__ gam, const float* __restrict__ gate,
    const float* __restrict__ onw, __hip_bfloat16* __restrict__ go) {
  const int task = blockIdx.x;
  const int bh = task >> 4, n = task & 15;
  const int b = bh >> 4, h = bh & 15;
  const int t0 = n * C_;
  const int tid = threadIdx.x;
  const int rowg = tid >> 4, colg = tid & 15;
  const int r8 = rowg * 8, c4 = colg * 4;
  __shared__ float At[64][68];
  __shared__ float Bs[64][132];
  __shared__ float lgam[64];
  if (tid < 64) lgam[tid] = gam[(size_t)task * 64 + tid];
  __syncthreads();
  const int t2 = tid >> 1, dh = (tid & 1) * 32;
  {
    const float* src = q + (((size_t)b * T_ + t0 + t2) * H_ + h) * DK_ + dh;
    const float sc = lgam[t2];
#pragma unroll
    for (int i = 0; i < 8; ++i) {
      const float4 v = ((const float4*)src)[i];
      At[dh + 4 * i + 0][t2] = v.x * sc; At[dh + 4 * i + 1][t2] = v.y * sc;
      At[dh + 4 * i + 2][t2] = v.z * sc; At[dh + 4 * i + 3][t2] = v.w * sc;
    }
  }
  {
    const float* src = Sst + (size_t)task * 8192 + t2 * 128 + (tid & 1) * 64;
    float* dst = &Bs[t2][(tid & 1) * 64];
#pragma unroll
    for (int i = 0; i < 16; ++i) ((float4*)dst)[i] = ((const float4*)src)[i];
  }
  __syncthreads();
  float acc[8][8];
#pragma unroll
  for (int i = 0; i < 8; ++i)
#pragma unroll
    for (int c = 0; c < 8; ++c) acc[i][c] = 0.f;
#pragma unroll 1
  for (int ph = 0; ph < 2; ++ph) {
    for (int kb = 0; kb < 64; kb += 4) {
#pragma unroll
      for (int j = 0; j < 4; ++j) {
        const float4 alo = *(const float4*)&At[kb + j][r8];
        const float4 ahi = *(const float4*)&At[kb + j][r8 + 4];
        const float4 blo = *(const float4*)&Bs[kb + j][c4];
        const float4 bhi = *(const float4*)&Bs[kb + j][c4 + 64];
        const float av[8] = {alo.x, alo.y, alo.z, alo.w, ahi.x, ahi.y, ahi.z, ahi.w};
        const float bv[8] = {blo.x, blo.y, blo.z, blo.w, bhi.x, bhi.y, bhi.z, bhi.w};
#pragma unroll
        for (int i = 0; i < 8; ++i)
#pragma unroll
          for (int c = 0; c < 8; ++c) acc[i][c] += av[i] * bv[c];
      }
    }
    if (ph == 0) {
      __syncthreads();
      {
        const float* src = qkd + (size_t)task * 4096 + t2 * 64 + dh;
#pragma unroll
        for (int i = 0; i < 8; ++i) {
          const float4 v = ((const float4*)src)[i];
          At[dh + 4 * i + 0][t2] = v.x; At[dh + 4 * i + 1][t2] = v.y;
          At[dh + 4 * i + 2][t2] = v.z; At[dh + 4 * i + 3][t2] = v.w;
        }
      }
      {
        const float* src = ub + (((size_t)b * T_ + t0 + t2) * H_ + h) * DV_ + (tid & 1) * 64;
        float* dst = &Bs[t2][(tid & 1) * 64];
#pragma unroll
        for (int i = 0; i < 16; ++i) ((float4*)dst)[i] = ((const float4*)src)[i];
      }
      __syncthreads();
    }
  }
#pragma unroll
  for (int i = 0; i < 8; ++i) {
    float pr = 0.f;
#pragma unroll
    for (int c = 0; c < 8; ++c) pr += acc[i][c] * acc[i][c];
    pr += __shfl_xor(pr, 1, 64);
    pr += __shfl_xor(pr, 2, 64);
    pr += __shfl_xor(pr, 4, 64);
    pr += __shfl_xor(pr, 8, 64);
    const float rms = rsqrtf(pr / (float)DV_ + 1e-5f);
    const size_t rb = (((size_t)b * T_ + t0 + r8 + i) * H_ + h) * DV_;
    const float4 glo = *(const float4*)(gate + rb + c4);
    const float4 ghi = *(const float4*)(gate + rb + c4 + 64);
    const float gv[8] = {glo.x, glo.y, glo.z, glo.w, ghi.x, ghi.y, ghi.z, ghi.w};
    unsigned short outv[8];
#pragma unroll
    for (int c = 0; c < 8; ++c) {
      const int col = (c < 4) ? c4 + c : c4 + 60 + c;
      const float gg = gv[c];
      const float val = acc[i][c] * rms * onw[col] * gg * (1.f / (1.f + __expf(-gg)));
      const __hip_bfloat16 bfv = __float2bfloat16(val);
      outv[c] = *(const unsigned short*)&bfv;
    }
    *(ushort4*)((unsigned short*)go + rb + c4) =
        make_ushort4(outv[0], outv[1], outv[2], outv[3]);
    *(ushort4*)((unsigned short*)go + rb + c4 + 64) =
        make_ushort4(outv[4], outv[5], outv[6], outv[7]);
  }
}

// ---------------------------------------------------------------------------
extern "C" void kernel_launch(void* const* d_in, const int* in_sizes, int n_in,
                              void* d_out, int out_size, void* d_ws, size_t ws_size,
                              hipStream_t stream) {
  const float* x    = (const float*)d_in[0];
  const float* n1w  = (const float*)d_in[1];
  const float* n2w  = (const float*)d_in[2];
  const float* Wq   = (const float*)d_in[3];
  const float* Wk   = (const float*)d_in[4];
  const float* Wv   = (const float*)d_in[5];
  const float* cq   = (const float*)d_in[6];
  const float* ck   = (const float*)d_in[7];
  const float* cv   = (const float*)d_in[8];
  const float* Wa   = (const float*)d_in[9];
  const float* Wb   = (const float*)d_in[10];
  const float* dtb  = (const float*)d_in[11];
  const float* Alog = (const float*)d_in[12];
  const float* Wg   = (const float*)d_in[13];
  const float* onw  = (const float*)d_in[14];
  const float* Wo   = (const float*)d_in[15];
  const float* W1   = (const float*)d_in[16];
  const float* W3   = (const float*)d_in[17];
  const float* W2   = (const float*)d_in[18];
  float* out = (float*)d_out;
  float* ws  = (float*)d_ws;

  const size_t SZ_MD = (size_t)M_ * D_;          // 2M floats
  const size_t SZ_MV = (size_t)M_ * H_ * DV_;    // 4M floats
  float* h    = ws;                               // [0,2M)  -> WT -> go_bf/h2_bf
  float* pq   = ws + SZ_MD;                       // [2M,4M)  -> proj rows -> QKd -> y1
  float* pk   = ws + 2 * SZ_MD;                   // [4M,6M)  -> proj rows -> kdtT
  float* pv   = ws + 3 * SZ_MD;                   // [6M,10M) -> proj rows -> S_store -> a1
  float* gate = ws + 3 * SZ_MD + SZ_MV;           // [10M,14M)
  float* qb   = ws + 3 * SZ_MD + 2 * SZ_MV;       // [14M,16M)
  float* kb   = ws + 4 * SZ_MD + 2 * SZ_MV;       // [16M,18M)
  float* vb   = ws + 5 * SZ_MD + 2 * SZ_MV;       // [18M,22M) in-place u -> Û
  float* Sst  = pv;
  float* y1   = pq;
  float* a1   = pv;
  float* wtb  = h;                                // transposed W for chunk_rec
  float* proj = pq;                               // merged q|k|v proj [M][4096]
  float* smalls = ws + 5 * SZ_MD + 3 * SZ_MV;     // 22M
  float* pa  = smalls;
  float* pb  = pa + (size_t)M_ * H_;
  float* gv  = pb + (size_t)M_ * H_;
  float* bv  = gv + (size_t)M_ * H_;
  float* gam = bv + (size_t)M_ * H_;
  __hip_bfloat16* h_bf  = (__hip_bfloat16*)vb;
  __hip_bfloat16* wb1   = (__hip_bfloat16*)kb;    // [4096][1024] bf16 = 8MB
  __hip_bfloat16* wb2   = (__hip_bfloat16*)vb;
  __hip_bfloat16* go_bf = (__hip_bfloat16*)h;
  __hip_bfloat16* h2_bf = (__hip_bfloat16*)h;
  __hip_bfloat16* a1b   = (__hip_bfloat16*)qb;

  const dim3 blk256(256);
  const dim3 g_tr1024_1024(1024 / 32, 1024 / 32);
  const dim3 g_tr1024_2048(2048 / 32, 1024 / 32);
  const dim3 g_tr2048_1024(1024 / 32, 2048 / 32);
  const dim3 g_tr1024_2816(2816 / 32, 1024 / 32);
  const dim3 g_tr2816_1024(1024 / 32, 2816 / 32);

  rmsnorm_k<<<dim3(M_), blk256, 0, stream>>>(x, n1w, h, h_bf, D_, 1e-6f);
  // merged q|k|v projection: Wqkv^T = [4096][1024] bf16 in wb1
  transpose_bf16_k<<<g_tr1024_1024, blk256, 0, stream>>>(Wq, wb1, D_, 1024);
  transpose_bf16_k<<<g_tr1024_1024, blk256, 0, stream>>>(Wk, wb1 + (size_t)1024 * 1024, D_, 1024);
  transpose_bf16_k<<<g_tr1024_2048, blk256, 0, stream>>>(Wv, wb1 + (size_t)2048 * 1024, D_, 2048);
  mfma_gemm_k<128, 128><<<dim3(4096 / 128, M_ / 128), blk256, 0, stream>>>(h_bf, wb1, nullptr, proj, M_, 4096, D_, 0);
  transpose_bf16_k<<<g_tr1024_2048, blk256, 0, stream>>>(Wg, wb1, D_, 2048);
  mfma_gemm_k<128, 64><<<dim3(2048 / 64, M_ / 128), blk256, 0, stream>>>(h_bf, wb1, nullptr, gate, M_, 2048, D_, 0);
  skinny_k<<<dim3(M_), blk256, 0, stream>>>(h, Wa, Wb, pa, pb, D_);
  conv_silu_k<<<dim3(M_), blk256, 0, stream>>>(proj, cq, qb, H_ * DK_, 4096, 0);
  conv_silu_k<<<dim3(M_), blk256, 0, stream>>>(proj, ck, kb, H_ * DK_, 4096, 1024);
  conv_silu_k<<<dim3(M_), blk256, 0, stream>>>(proj, cv, vb, H_ * DV_, 4096, 2048);
  beta_g_k<<<dim3((M_ * H_ + 255) / 256), blk256, 0, stream>>>(pa, pb, dtb, Alog, gv, bv, M_ * H_);
  l2norm_k<<<dim3(M_ * H_), dim3(64), 0, stream>>>(qb, 0.125f);
  l2norm_k<<<dim3(M_ * H_), dim3(64), 0, stream>>>(kb, 1.0f);
  chunk_prep_k<<<dim3(32 * NCH), blk256, 0, stream>>>(qb, kb, vb, gv, bv, pq, pk, gam, wtb);
  chunk_rec_k<<<dim3(256), blk256, 0, stream>>>(wtb, vb, pk, gam, Sst);
  chunk_o_k<<<dim3(32 * NCH), dim3(128), 0, stream>>>(qb, pq, vb, Sst, gam, gate, onw, go_bf);
  transpose_bf16_k<<<g_tr2048_1024, blk256, 0, stream>>>(Wo, wb2, H_ * DV_, 1024);
  mfma_gemm_k<64, 64><<<dim3(1024 / 64, M_ / 64), blk256, 0, stream>>>(go_bf, wb2, x, y1, M_, 1024, H_ * DV_, 1);
  rmsnorm_k<<<dim3(M_), blk256, 0, stream>>>(y1, n2w, nullptr, h2_bf, D_, 1e-6f);
  transpose_bf16_k<<<g_tr1024_2816, blk256, 0, stream>>>(W1, wb2, D_, FH_);
  mfma_gemm_k<128, 128><<<dim3(FH_ / 128, M_ / 128), blk256, 0, stream>>>(h2_bf, wb2, nullptr, a1, M_, FH_, D_, 0);
  transpose_bf16_k<<<g_tr1024_2816, blk256, 0, stream>>>(W3, wb2, D_, FH_);
  mfma_gemm_k<128, 128><<<dim3(FH_ / 128, M_ / 128), blk256, 0, stream>>>(h2_bf, wb2, a1, a1b, M_, FH_, D_, 2);
  transpose_bf16_k<<<g_tr2816_1024, blk256, 0, stream>>>(W2, wb2, FH_, 1024);
  mfma_gemm_k<64, 64><<<dim3(1024 / 64, M_ / 64), blk256, 0, stream>>>(a1b, wb2, y1, out, M_, 1024, FH_, 1);
}

// Round 14
// 558.229 us; speedup vs baseline: 1.0147x; 1.0147x over previous
//
#include <hip/hip_runtime.h>
#include <hip/hip_bf16.h>
#include <math.h>

// Problem constants
#define B_  2
#define T_  1024
#define D_  1024
#define H_  16
#define DK_ 64
#define DV_ 128
#define FH_ 2816
#define M_  (B_ * T_)   // 2048 tokens
#define C_  64          // chunk length
#define NCH (T_ / C_)   // 16 chunks

typedef __attribute__((ext_vector_type(8))) short bf16x8;
typedef __attribute__((ext_vector_type(4))) float f32x4;

// ---------------------------------------------------------------------------
// rmsnorm with fp32 and/or bf16 outputs (either may be null)
__global__ __launch_bounds__(256) void rmsnorm_k(
    const float* __restrict__ x, const float* __restrict__ w,
    float* __restrict__ outf, __hip_bfloat16* __restrict__ outb,
    int D, float eps) {
  const int row = blockIdx.x;
  const float* xr = x + (size_t)row * D;
  float ss = 0.f;
  for (int i = threadIdx.x; i < D; i += blockDim.x) { float v = xr[i]; ss += v * v; }
  for (int off = 32; off > 0; off >>= 1) ss += __shfl_xor(ss, off, 64);
  __shared__ float wsum[4];
  __shared__ float s_scale;
  const int lane = threadIdx.x & 63, wid = threadIdx.x >> 6;
  if (lane == 0) wsum[wid] = ss;
  __syncthreads();
  if (threadIdx.x == 0) {
    float tot = 0.f;
    const int nw = blockDim.x >> 6;
    for (int i = 0; i < nw; ++i) tot += wsum[i];
    s_scale = rsqrtf(tot / (float)D + eps);
  }
  __syncthreads();
  const float sc = s_scale;
  for (int i = threadIdx.x; i < D; i += blockDim.x) {
    const float v = xr[i] * sc * w[i];
    if (outf) outf[(size_t)row * D + i] = v;
    if (outb) outb[(size_t)row * D + i] = __float2bfloat16(v);
  }
}

// ---------------------------------------------------------------------------
// Tiled transpose + fp32->bf16 convert: W[K,N] -> Wt[N,K]
__global__ __launch_bounds__(256) void transpose_bf16_k(
    const float* __restrict__ W, __hip_bfloat16* __restrict__ Wt, int K, int N) {
  __shared__ float t[32][33];
  const int k0 = blockIdx.y * 32, n0 = blockIdx.x * 32;
  const int c = threadIdx.x & 31, r = threadIdx.x >> 5;  // r in 0..7
#pragma unroll
  for (int i = 0; i < 4; ++i)
    t[r + 8 * i][c] = W[(size_t)(k0 + r + 8 * i) * N + n0 + c];
  __syncthreads();
#pragma unroll
  for (int i = 0; i < 4; ++i)
    Wt[(size_t)(n0 + r + 8 * i) * K + k0 + c] = __float2bfloat16(t[c][r + 8 * i]);
}

// ---------------------------------------------------------------------------
__device__ __forceinline__ void gload_lds16(const void* g, void* l) {
  __builtin_amdgcn_global_load_lds(
      (const __attribute__((address_space(1))) void*)g,
      (__attribute__((address_space(3))) void*)l, 16, 0, 0);
}

// bf16 MFMA GEMM: C[M,N] = A[M,K] @ Bt[N,K]^T.  Tile BM x BN (64/128 each).
// BK=64 (two linear [BM][32] sub-tiles) + 2-phase double-buffered staging.
// Round-13 tile policy (dispatch-level packing trumps per-wave LDS ratio —
// round-12 lesson): 128x128 ONLY where grid is an exact multiple of 256
// (proj: 512 blocks = 2/CU, no tail). W1/W3 at 128x128 gave 352 blocks with
// a 2/CU LDS cap -> 96-block tail on 256 CUs (~27% idle) and regressed
// 40->48.5us; reverted to 128x64 (704 blocks, 3/CU cap, well-packed).
// mode 0: C = acc (fp32); mode 1: C = acc + res (fp32);
// mode 2: Cbf16 = silu(res) * acc   (fused SwiGLU epilogue)
template<int BM, int BN>
__global__ __launch_bounds__(256) void mfma_gemm_k(
    const __hip_bfloat16* __restrict__ A, const __hip_bfloat16* __restrict__ Bt,
    const float* __restrict__ res, void* __restrict__ Cout,
    int M, int N, int K, int mode) {
  __shared__ __hip_bfloat16 As[2][BM * 64];   // two [BM][32] sub-tiles each
  __shared__ __hip_bfloat16 Bs[2][BN * 64];
  constexpr int MF = BM / 32;        // a-frags per wave (4 or 2)
  constexpr int NF = BN / 32;        // b-frags per wave (4 or 2)
  const int tid = threadIdx.x;
  const int lane = tid & 63;
  const int wv = tid >> 6;
  const int wm = (wv >> 1) * (BM / 2), wn = (wv & 1) * (BN / 2);
  const int bm = blockIdx.y * BM, bn = blockIdx.x * BN;
  const int l15 = lane & 15, lq8 = (lane >> 4) * 8;
  const int ar = tid >> 2;
  const int ac = (tid & 3) * 8;
  const size_t Abase = (size_t)(bm + ar) * K + ac;
  const size_t Bbase = (size_t)(bn + ar) * K + ac;
  f32x4 acc[MF][NF];
#pragma unroll
  for (int i = 0; i < MF; ++i)
#pragma unroll
    for (int j = 0; j < NF; ++j) acc[i][j] = (f32x4){0.f, 0.f, 0.f, 0.f};

  // stage 64-wide k-slab [k0,k0+64) into buffer buf as two linear sub-tiles
  auto stage = [&](int buf, int k0) {
#pragma unroll
    for (int s = 0; s < 2; ++s) {
      const int kk = k0 + 32 * s;
      char* dA = (char*)&As[buf][s * BM * 32] + tid * 16;
      gload_lds16(A + Abase + kk, dA);
      if constexpr (BM == 128)
        gload_lds16(A + Abase + (size_t)64 * K + kk, dA + 4096);
      char* dB = (char*)&Bs[buf][s * BN * 32] + tid * 16;
      gload_lds16(Bt + Bbase + kk, dB);
      if constexpr (BN == 128)
        gload_lds16(Bt + Bbase + (size_t)64 * K + kk, dB + 4096);
    }
  };

  stage(0, 0);
  __syncthreads();                 // implicit vmcnt(0): buf0 ready
  int cur = 0;
#pragma unroll 2
  for (int k0 = 0; k0 < K; k0 += 64) {
    if (k0 + 64 < K) stage(cur ^ 1, k0 + 64);   // in flight during compute
#pragma unroll
    for (int s = 0; s < 2; ++s) {
      bf16x8 af[MF], bfr[NF];
#pragma unroll
      for (int i = 0; i < MF; ++i)
        af[i] = *(const bf16x8*)(&As[cur][s * BM * 32] + (wm + i * 16 + l15) * 32 + lq8);
#pragma unroll
      for (int j = 0; j < NF; ++j)
        bfr[j] = *(const bf16x8*)(&Bs[cur][s * BN * 32] + (wn + j * 16 + l15) * 32 + lq8);
#pragma unroll
      for (int i = 0; i < MF; ++i)
#pragma unroll
        for (int j = 0; j < NF; ++j)
          acc[i][j] = __builtin_amdgcn_mfma_f32_16x16x32_bf16(af[i], bfr[j], acc[i][j], 0, 0, 0);
    }
    __syncthreads();               // drains the k0+64 glds AFTER compute
    cur ^= 1;
  }
  const int r0 = (lane >> 4) * 4;
#pragma unroll
  for (int i = 0; i < MF; ++i) {
#pragma unroll
    for (int j = 0; j < NF; ++j) {
      const int row = bm + wm + i * 16 + r0;
      const int col = bn + wn + j * 16 + l15;
#pragma unroll
      for (int r = 0; r < 4; ++r) {
        const size_t idx = (size_t)(row + r) * N + col;
        const float a = acc[i][j][r];
        if (mode == 0) ((float*)Cout)[idx] = a;
        else if (mode == 1) ((float*)Cout)[idx] = a + res[idx];
        else {
          const float s = res[idx];
          ((__hip_bfloat16*)Cout)[idx] =
              __float2bfloat16(s * (1.f / (1.f + __expf(-s))) * a);
        }
      }
    }
  }
}

// ---------------------------------------------------------------------------
// pa/pb = h @ [Wa|Wb] — all 256 threads active (8-way K-split + reduce).
__global__ __launch_bounds__(256) void skinny_k(
    const float* __restrict__ h, const float* __restrict__ Wa,
    const float* __restrict__ Wb, float* __restrict__ pa,
    float* __restrict__ pb, int K) {
  __shared__ float hl[D_];
  __shared__ float red[8][32];
  const int row = blockIdx.x;
  const int tid = threadIdx.x;
  {
    const float4* src = (const float4*)(h + (size_t)row * K);
    ((float4*)hl)[tid] = src[tid];
  }
  __syncthreads();
  const int col = tid & 31, sub = tid >> 5;
  const float* W = (col < 16) ? Wa : Wb;
  const int cc = col & 15;
  float s = 0.f;
  const int kk0 = sub * 128;
  for (int k = kk0; k < kk0 + 128; ++k) s += hl[k] * W[k * H_ + cc];
  red[sub][col] = s;
  __syncthreads();
  if (tid < 32) {
    float t = 0.f;
#pragma unroll
    for (int i = 0; i < 8; ++i) t += red[i][tid];
    if (tid < 16) pa[(size_t)row * H_ + tid] = t;
    else          pb[(size_t)row * H_ + tid - 16] = t;
  }
}

// ---------------------------------------------------------------------------
// causal depthwise conv + silu. Row stride / column offset parametrized so
// merged projection buffers ([M][4096] q|k|v) can be consumed in place.
__global__ __launch_bounds__(256) void conv_silu_k(
    const float* __restrict__ src, const float* __restrict__ w,
    float* __restrict__ dst, int C, int sstr, int soff) {
  const int bt = blockIdx.x;
  const int b = bt / T_, t = bt % T_;
  const float* s = src + (size_t)b * T_ * sstr + soff;
  for (int c = threadIdx.x; c < C; c += blockDim.x) {
    const float w0 = w[c * 4 + 0], w1 = w[c * 4 + 1],
                w2 = w[c * 4 + 2], w3 = w[c * 4 + 3];
    float acc = s[(size_t)t * sstr + c] * w3;
    if (t >= 1) acc += s[(size_t)(t - 1) * sstr + c] * w2;
    if (t >= 2) acc += s[(size_t)(t - 2) * sstr + c] * w1;
    if (t >= 3) acc += s[(size_t)(t - 3) * sstr + c] * w0;
    dst[(size_t)bt * C + c] = acc * (1.f / (1.f + __expf(-acc)));
  }
}

// ---------------------------------------------------------------------------
__global__ void beta_g_k(const float* __restrict__ pa, const float* __restrict__ pb,
                         const float* __restrict__ dtb, const float* __restrict__ Alog,
                         float* __restrict__ g, float* __restrict__ beta, int n) {
  const int i = blockIdx.x * blockDim.x + threadIdx.x;
  if (i >= n) return;
  const int h = i & (H_ - 1);
  const float xx = pa[i] + dtb[h];
  const float sp = (xx > 20.f) ? xx : log1pf(expf(xx));
  g[i] = -expf(Alog[h]) * sp;
  beta[i] = 1.f / (1.f + expf(-pb[i]));
}

// ---------------------------------------------------------------------------
__global__ __launch_bounds__(64) void l2norm_k(float* __restrict__ q, float scale) {
  const size_t row = blockIdx.x;
  const int lane = threadIdx.x;
  const float v = q[row * 64 + lane];
  float ss = v * v;
  for (int off = 32; off > 0; off >>= 1) ss += __shfl_xor(ss, off, 64);
  q[row * 64 + lane] = v * rsqrtf(ss + 1e-6f) * scale;
}

// ---------------------------------------------------------------------------
// Chunked gated delta rule, phase A. Barrier-free solve (round 8).
__global__ __launch_bounds__(256) void chunk_prep_k(
    const float* __restrict__ q, float* __restrict__ k, float* __restrict__ v,
    const float* __restrict__ g, const float* __restrict__ beta,
    float* __restrict__ qkd, float* __restrict__ kdt, float* __restrict__ gam,
    float* __restrict__ wt) {
  const int task = blockIdx.x;
  const int bh = task >> 4, n = task & (NCH - 1);
  const int b = bh >> 4, h = bh & 15;
  const int t0 = n * C_;
  const int tid = threadIdx.x;
  __shared__ float lk[C_][68];     // staged k rows
  __shared__ float Gs[C_][68];     // strict-lower β-folded Gram (zeros above)
  __shared__ float Xs[C_][100];    // 96-column RHS/solution panel
  __shared__ float Td[4][16][17];  // 16x16 diagonal-block inverses
  __shared__ float lb[C_], lgam[C_], lbeta[C_], lbg[C_];
  // stage k chunk
  {
    const int r = tid >> 2, cq = (tid & 3) * 16;
    const float* src = k + (((size_t)b * T_ + t0 + r) * H_ + h) * DK_ + cq;
#pragma unroll
    for (int i = 0; i < 4; ++i)
      *(float4*)&lk[r][cq + 4 * i] = ((const float4*)src)[i];
  }
  // g cumsum (wave 0), γ, β, βγ
  if (tid < 64) {
    const size_t gi = ((size_t)b * T_ + t0 + tid) * H_ + h;
    float xx = g[gi];
    const float bb = beta[gi];
    lbeta[tid] = bb;
#pragma unroll
    for (int off = 1; off < 64; off <<= 1) {
      float y = __shfl_up(xx, off, 64);
      if (tid >= off) xx += y;
    }
    lb[tid] = xx;
    const float gm = __expf(xx);
    lgam[tid] = gm;
    lbg[tid] = bb * gm;
  }
  __syncthreads();
  const int r4g = (tid >> 4) * 4;
  const int sl = tid & 15;
  // Gram: G = β-folded strict-lower K K^T decay; QKd = (Q K^T) decay
  {
    const float* qg = q + (((size_t)b * T_ + t0) * H_ + h) * DK_;
    float accA[4][4] = {};
    float accQ[4][4] = {};
    for (int d = 0; d < 64; d += 4) {
      float4 kt[4], ks[4], qt[4];
#pragma unroll
      for (int i = 0; i < 4; ++i) kt[i] = *(const float4*)&lk[r4g + i][d];
#pragma unroll
      for (int j = 0; j < 4; ++j) ks[j] = *(const float4*)&lk[sl + 16 * j][d];
#pragma unroll
      for (int i = 0; i < 4; ++i) qt[i] = *(const float4*)(qg + (size_t)(r4g + i) * (H_ * DK_) + d);
#pragma unroll
      for (int i = 0; i < 4; ++i)
#pragma unroll
        for (int j = 0; j < 4; ++j) {
          accA[i][j] += kt[i].x * ks[j].x + kt[i].y * ks[j].y + kt[i].z * ks[j].z + kt[i].w * ks[j].w;
          accQ[i][j] += qt[i].x * ks[j].x + qt[i].y * ks[j].y + qt[i].z * ks[j].z + qt[i].w * ks[j].w;
        }
    }
    float* qo = qkd + (size_t)task * 4096;
#pragma unroll
    for (int i = 0; i < 4; ++i)
#pragma unroll
      for (int j = 0; j < 4; ++j) {
        const int t = r4g + i, s = sl + 16 * j;
        const float dec = (s <= t) ? __expf(lb[t] - lb[s]) : 0.f;
        Gs[t][s] = (t > s) ? lbeta[t] * accA[i][j] * dec : 0.f;
        qo[t * 64 + s] = accQ[i][j] * dec;
      }
  }
  // kdtT[s][dk] = k[s][dk] * exp(bC - lb[s])  (coalesced rows, 1 exp/thread)
  {
    const int s = tid >> 2, dq = (tid & 3) * 16;
    const float e = __expf(lb[63] - lb[s]);
    float* dst = kdt + (size_t)task * 4096 + s * 64 + dq;
#pragma unroll
    for (int m = 0; m < 4; ++m) {
      float4 kv = *(const float4*)&lk[s][dq + 4 * m];
      kv.x *= e; kv.y *= e; kv.z *= e; kv.w *= e;
      *(float4*)(dst + 4 * m) = kv;
    }
  }
  if (tid < 64) gam[(size_t)task * 64 + tid] = lgam[tid];
  __syncthreads();
  // Td (threads 0..63: 4 blocks x 16 columns, registers only) + RHS0 load
  if (tid < 64) {
    const int blk = tid >> 4, cI = tid & 15;
    float Xc[16];
#pragma unroll
    for (int t = 0; t < 16; ++t) Xc[t] = (t == cI) ? 1.f : 0.f;
#pragma unroll
    for (int t = 1; t < 16; ++t) {
      float acc = 0.f;
#pragma unroll
      for (int s = 0; s < t; ++s)
        acc += Gs[blk * 16 + t][blk * 16 + s] * Xc[s];
      Xc[t] -= acc;
    }
#pragma unroll
    for (int t = 0; t < 16; ++t) Td[blk][t][cI] = Xc[t];
  } else {
    // RHS half 0: βV columns 0..95 (192 threads, 32 cells each)
    for (int idx = tid - 64; idx < 64 * 96; idx += 192) {
      const int t = idx / 96, c = idx % 96;
      Xs[t][c] = lbeta[t] * v[(((size_t)b * T_ + t0 + t) * H_ + h) * DV_ + c];
    }
  }
  __syncthreads();
  const int rt = tid & 15;          // row within block
  const int cg = tid >> 4;          // column group: cols cg*6 .. cg*6+5
#pragma unroll 1
  for (int half = 0; half < 2; ++half) {
    // 4-stage blocked sweep — BARRIER-FREE (quarter-wave column ownership;
    // same-wave LDS forwarding)
#pragma unroll
    for (int bi = 0; bi < 4; ++bi) {
      if (bi > 0) {
        float acc[6] = {0.f, 0.f, 0.f, 0.f, 0.f, 0.f};
        for (int kk = 0; kk < 16 * bi; ++kk) {
          const float gvv = Gs[16 * bi + rt][kk];
#pragma unroll
          for (int c = 0; c < 6; ++c) acc[c] += gvv * Xs[kk][cg * 6 + c];
        }
#pragma unroll
        for (int c = 0; c < 6; ++c) Xs[16 * bi + rt][cg * 6 + c] -= acc[c];
      }
      float y[6] = {0.f, 0.f, 0.f, 0.f, 0.f, 0.f};
#pragma unroll
      for (int s = 0; s < 16; ++s) {
        const float tv = Td[bi][rt][s];
#pragma unroll
        for (int c = 0; c < 6; ++c) y[c] += tv * Xs[16 * bi + s][cg * 6 + c];
      }
#pragma unroll
      for (int c = 0; c < 6; ++c) Xs[16 * bi + rt][cg * 6 + c] = y[c];
    }
    __syncthreads();   // solve complete -> all-thread writeback
    // writeback + next RHS
    if (half == 0) {
      for (int idx = tid; idx < 64 * 96; idx += 256) {
        const int t = idx / 96, c = idx % 96;
        v[(((size_t)b * T_ + t0 + t) * H_ + h) * DV_ + c] = Xs[t][c];
      }
      __syncthreads();   // writeback reads done before RHS overwrite
      // RHS half 1: cols 0..31 = βV cols 96..127; cols 32..95 = βγ·K cols 0..63
      for (int idx = tid; idx < 64 * 96; idx += 256) {
        const int t = idx / 96, c = idx % 96;
        if (c < 32)
          Xs[t][c] = lbeta[t] * v[(((size_t)b * T_ + t0 + t) * H_ + h) * DV_ + 96 + c];
        else
          Xs[t][c] = lbg[t] * lk[t][c - 32];
      }
      __syncthreads();   // RHS visible to solver quarter-waves
    } else {
      // v cols 96..127
      for (int idx = tid; idx < 64 * 32; idx += 256) {
        const int t = idx >> 5, cc = idx & 31;
        v[(((size_t)b * T_ + t0 + t) * H_ + h) * DV_ + 96 + cc] = Xs[t][cc];
      }
      // wt[task][dk][t] = Xs[t][32+dk]  (transposed W; coalesced per-thread rows)
      {
        const int dk = tid & 63, tg = tid >> 6;
        float buf[16];
#pragma unroll
        for (int j = 0; j < 16; ++j) buf[j] = Xs[16 * tg + j][32 + dk];
        float* dst = wt + (size_t)task * 4096 + dk * 64 + 16 * tg;
#pragma unroll
        for (int m = 0; m < 4; ++m)
          *(float4*)(dst + 4 * m) =
              make_float4(buf[4 * m], buf[4 * m + 1], buf[4 * m + 2], buf[4 * m + 3]);
      }
    }
  }
}

// ---------------------------------------------------------------------------
// Serial recurrence — round-9 256-thread version (best measured: 46.6us).
__global__ __launch_bounds__(256) void chunk_rec_k(
    const float* __restrict__ WT, float* __restrict__ u,
    const float* __restrict__ kdtT, const float* __restrict__ gam,
    float* __restrict__ Sst) {
  const int bh = blockIdx.x & 31, cg = blockIdx.x >> 5;   // XCD swizzle kept
  const int b = bh >> 4, h = bh & 15;
  const int c0 = cg * 16;
  const int tid = threadIdx.x;
  const int w = tid >> 6;             // wave 0..3
  const int lane = tid & 63;
  const int L15 = lane & 15;
  const int t4 = L15 * 4;             // 4 rows (tokens in mm1 / dk in mm2)
  const int c = w * 4 + (lane >> 4);  // owned column (0..15)
  const int iot = tid >> 2;           // I/O ownership: row 0..63
  const int ioq = (tid & 3) * 4;      // I/O col quad base

  __shared__ float Wt[2][64 * 64];    // [buf][dk*64+token]  (linear, glds dest)
  __shared__ float Kt[2][64 * 64];    // [buf][s*64+dk]
  __shared__ float SsT[16][68];       // S^T [col][dk]
  __shared__ float UbT[16][68];       // U^T [col][s]
  __shared__ float Ub0[64][17];       // staged u [t][col]

  float Sr[4];
#pragma unroll
  for (int i = 0; i < 4; ++i) Sr[i] = 0.f;
#pragma unroll
  for (int i = 0; i < 4; ++i) SsT[c][t4 + i] = 0.f;

  // prologue: glds chunk 0 into buffer 0 (each wave stages its row quarter)
  {
    const float* sW = WT + (size_t)(bh * NCH) * 4096 + w * 1024 + lane * 4;
    const float* sK = kdtT + (size_t)(bh * NCH) * 4096 + w * 1024 + lane * 4;
    char* lW = (char*)&Wt[0][w * 1024] + lane * 16;
    char* lK = (char*)&Kt[0][w * 1024] + lane * 16;
#pragma unroll
    for (int i = 0; i < 4; ++i) {
      gload_lds16(sW + i * 256, lW + i * 1024);
      gload_lds16(sK + i * 256, lK + i * 1024);
    }
  }
  __syncthreads();

#pragma unroll 1
  for (int n = 0; n < NCH; ++n) {
    const int cur = n & 1, nx = cur ^ 1;
    const int task = bh * NCH + n;
    const int t0 = n * C_;
    const int n1 = (n + 1 < NCH) ? n + 1 : NCH - 1;   // clamped (no branch BB)
    const int task1 = bh * NCH + n1;
    const float gC = gam[(size_t)task * 64 + 63];

    // A1: issue coalesced u load FIRST (its wait then leaves glds in flight)
    const float4 uv = *(const float4*)(
        u + (((size_t)b * T_ + t0 + iot) * H_ + h) * DV_ + c0 + ioq);
    // A2: issue next-chunk glds staging (drained at bar1; hidden under mm1)
    {
      const float* sW = WT + (size_t)task1 * 4096 + w * 1024 + lane * 4;
      const float* sK = kdtT + (size_t)task1 * 4096 + w * 1024 + lane * 4;
      char* lW = (char*)&Wt[nx][w * 1024] + lane * 16;
      char* lK = (char*)&Kt[nx][w * 1024] + lane * 16;
#pragma unroll
      for (int i = 0; i < 4; ++i) {
        gload_lds16(sW + i * 256, lW + i * 1024);
        gload_lds16(sK + i * 256, lK + i * 1024);
      }
    }
    __builtin_amdgcn_sched_barrier(0);
    // A3: Sst writeback (pre-chunk state, coalesced; reads SsT cross-wave,
    //     ordered by prior bar2 / init)
    {
      float4 sv;
      sv.x = SsT[ioq + 0][iot]; sv.y = SsT[ioq + 1][iot];
      sv.z = SsT[ioq + 2][iot]; sv.w = SsT[ioq + 3][iot];
      *(float4*)(Sst + (size_t)task * 8192 + iot * 128 + c0 + ioq) = sv;
    }
    // A4: mm1: acc[i] = sum_k W[t4+i][k] * S[k][c]
    float4 srow[16];
#pragma unroll
    for (int g = 0; g < 16; ++g) srow[g] = *(const float4*)&SsT[c][4 * g];
    float acc[4] = {0.f, 0.f, 0.f, 0.f};
#pragma unroll
    for (int g = 0; g < 16; ++g) {
      const float sj[4] = {srow[g].x, srow[g].y, srow[g].z, srow[g].w};
#pragma unroll
      for (int j = 0; j < 4; ++j) {
        const float4 wv = *(const float4*)&Wt[cur][(4 * g + j) * 64 + t4];
        acc[0] += wv.x * sj[j]; acc[1] += wv.y * sj[j];
        acc[2] += wv.z * sj[j]; acc[3] += wv.w * sj[j];
      }
    }
    // A5: commit staged u -> Ub0 (vmcnt wait covered by mm1)
    Ub0[iot][ioq + 0] = uv.x; Ub0[iot][ioq + 1] = uv.y;
    Ub0[iot][ioq + 2] = uv.z; Ub0[iot][ioq + 3] = uv.w;
    __syncthreads();  // bar1: Ub0 visible; glds for [nx] drained

    // B1: U-form (reads Ub0 cross-wave; writes UbT same-wave rows)
#pragma unroll
    for (int i = 0; i < 4; ++i)
      UbT[c][t4 + i] = Ub0[t4 + i][c] - acc[i];
    // B2: mm2: acc2[i] = sum_s K̂[s][t4+i] * U[s][c]  (same-wave UbT row)
    float4 urow[16];
#pragma unroll
    for (int g = 0; g < 16; ++g) urow[g] = *(const float4*)&UbT[c][4 * g];
    float ac2[4] = {0.f, 0.f, 0.f, 0.f};
#pragma unroll
    for (int g = 0; g < 16; ++g) {
      const float uj[4] = {urow[g].x, urow[g].y, urow[g].z, urow[g].w};
#pragma unroll
      for (int j = 0; j < 4; ++j) {
        const float4 kv = *(const float4*)&Kt[cur][(4 * g + j) * 64 + t4];
        ac2[0] += kv.x * uj[j]; ac2[1] += kv.y * uj[j];
        ac2[2] += kv.z * uj[j]; ac2[3] += kv.w * uj[j];
      }
    }
    // B3: state update + SsT write (same-wave rows)
#pragma unroll
    for (int i = 0; i < 4; ++i) {
      Sr[i] = gC * Sr[i] + ac2[i];
      SsT[c][t4 + i] = Sr[i];
    }
    __syncthreads();  // bar2: UbT/SsT complete

    // C: coalesced u writeback from UbT (cross-wave, ordered by bar2)
    {
      float4 ov;
      ov.x = UbT[ioq + 0][iot]; ov.y = UbT[ioq + 1][iot];
      ov.z = UbT[ioq + 2][iot]; ov.w = UbT[ioq + 3][iot];
      *(float4*)(u + (((size_t)b * T_ + t0 + iot) * H_ + h) * DV_ + c0 + ioq) = ov;
    }
  }
}

// ---------------------------------------------------------------------------
// Parallel O with fused gatenorm (unchanged).
__global__ __launch_bounds__(128) void chunk_o_k(
    const float* __restrict__ q, const float* __restrict__ qkd,
    const float* __restrict__ ub, const float* __restrict__ Sst,
    const float* __restrict__ gam, const float* __restrict__ gate,
    const float* __restrict__ onw, __hip_bfloat16* __restrict__ go) {
  const int task = blockIdx.x;
  const int bh = task >> 4, n = task & 15;
  const int b = bh >> 4, h = bh & 15;
  const int t0 = n * C_;
  const int tid = threadIdx.x;
  const int rowg = tid >> 4, colg = tid & 15;
  const int r8 = rowg * 8, c4 = colg * 4;
  __shared__ float At[64][68];
  __shared__ float Bs[64][132];
  __shared__ float lgam[64];
  if (tid < 64) lgam[tid] = gam[(size_t)task * 64 + tid];
  __syncthreads();
  const int t2 = tid >> 1, dh = (tid & 1) * 32;
  {
    const float* src = q + (((size_t)b * T_ + t0 + t2) * H_ + h) * DK_ + dh;
    const float sc = lgam[t2];
#pragma unroll
    for (int i = 0; i < 8; ++i) {
      const float4 v = ((const float4*)src)[i];
      At[dh + 4 * i + 0][t2] = v.x * sc; At[dh + 4 * i + 1][t2] = v.y * sc;
      At[dh + 4 * i + 2][t2] = v.z * sc; At[dh + 4 * i + 3][t2] = v.w * sc;
    }
  }
  {
    const float* src = Sst + (size_t)task * 8192 + t2 * 128 + (tid & 1) * 64;
    float* dst = &Bs[t2][(tid & 1) * 64];
#pragma unroll
    for (int i = 0; i < 16; ++i) ((float4*)dst)[i] = ((const float4*)src)[i];
  }
  __syncthreads();
  float acc[8][8];
#pragma unroll
  for (int i = 0; i < 8; ++i)
#pragma unroll
    for (int c = 0; c < 8; ++c) acc[i][c] = 0.f;
#pragma unroll 1
  for (int ph = 0; ph < 2; ++ph) {
    for (int kb = 0; kb < 64; kb += 4) {
#pragma unroll
      for (int j = 0; j < 4; ++j) {
        const float4 alo = *(const float4*)&At[kb + j][r8];
        const float4 ahi = *(const float4*)&At[kb + j][r8 + 4];
        const float4 blo = *(const float4*)&Bs[kb + j][c4];
        const float4 bhi = *(const float4*)&Bs[kb + j][c4 + 64];
        const float av[8] = {alo.x, alo.y, alo.z, alo.w, ahi.x, ahi.y, ahi.z, ahi.w};
        const float bv[8] = {blo.x, blo.y, blo.z, blo.w, bhi.x, bhi.y, bhi.z, bhi.w};
#pragma unroll
        for (int i = 0; i < 8; ++i)
#pragma unroll
          for (int c = 0; c < 8; ++c) acc[i][c] += av[i] * bv[c];
      }
    }
    if (ph == 0) {
      __syncthreads();
      {
        const float* src = qkd + (size_t)task * 4096 + t2 * 64 + dh;
#pragma unroll
        for (int i = 0; i < 8; ++i) {
          const float4 v = ((const float4*)src)[i];
          At[dh + 4 * i + 0][t2] = v.x; At[dh + 4 * i + 1][t2] = v.y;
          At[dh + 4 * i + 2][t2] = v.z; At[dh + 4 * i + 3][t2] = v.w;
        }
      }
      {
        const float* src = ub + (((size_t)b * T_ + t0 + t2) * H_ + h) * DV_ + (tid & 1) * 64;
        float* dst = &Bs[t2][(tid & 1) * 64];
#pragma unroll
        for (int i = 0; i < 16; ++i) ((float4*)dst)[i] = ((const float4*)src)[i];
      }
      __syncthreads();
    }
  }
#pragma unroll
  for (int i = 0; i < 8; ++i) {
    float pr = 0.f;
#pragma unroll
    for (int c = 0; c < 8; ++c) pr += acc[i][c] * acc[i][c];
    pr += __shfl_xor(pr, 1, 64);
    pr += __shfl_xor(pr, 2, 64);
    pr += __shfl_xor(pr, 4, 64);
    pr += __shfl_xor(pr, 8, 64);
    const float rms = rsqrtf(pr / (float)DV_ + 1e-5f);
    const size_t rb = (((size_t)b * T_ + t0 + r8 + i) * H_ + h) * DV_;
    const float4 glo = *(const float4*)(gate + rb + c4);
    const float4 ghi = *(const float4*)(gate + rb + c4 + 64);
    const float gv[8] = {glo.x, glo.y, glo.z, glo.w, ghi.x, ghi.y, ghi.z, ghi.w};
    unsigned short outv[8];
#pragma unroll
    for (int c = 0; c < 8; ++c) {
      const int col = (c < 4) ? c4 + c : c4 + 60 + c;
      const float gg = gv[c];
      const float val = acc[i][c] * rms * onw[col] * gg * (1.f / (1.f + __expf(-gg)));
      const __hip_bfloat16 bfv = __float2bfloat16(val);
      outv[c] = *(const unsigned short*)&bfv;
    }
    *(ushort4*)((unsigned short*)go + rb + c4) =
        make_ushort4(outv[0], outv[1], outv[2], outv[3]);
    *(ushort4*)((unsigned short*)go + rb + c4 + 64) =
        make_ushort4(outv[4], outv[5], outv[6], outv[7]);
  }
}

// ---------------------------------------------------------------------------
extern "C" void kernel_launch(void* const* d_in, const int* in_sizes, int n_in,
                              void* d_out, int out_size, void* d_ws, size_t ws_size,
                              hipStream_t stream) {
  const float* x    = (const float*)d_in[0];
  const float* n1w  = (const float*)d_in[1];
  const float* n2w  = (const float*)d_in[2];
  const float* Wq   = (const float*)d_in[3];
  const float* Wk   = (const float*)d_in[4];
  const float* Wv   = (const float*)d_in[5];
  const float* cq   = (const float*)d_in[6];
  const float* ck   = (const float*)d_in[7];
  const float* cv   = (const float*)d_in[8];
  const float* Wa   = (const float*)d_in[9];
  const float* Wb   = (const float*)d_in[10];
  const float* dtb  = (const float*)d_in[11];
  const float* Alog = (const float*)d_in[12];
  const float* Wg   = (const float*)d_in[13];
  const float* onw  = (const float*)d_in[14];
  const float* Wo   = (const float*)d_in[15];
  const float* W1   = (const float*)d_in[16];
  const float* W3   = (const float*)d_in[17];
  const float* W2   = (const float*)d_in[18];
  float* out = (float*)d_out;
  float* ws  = (float*)d_ws;

  const size_t SZ_MD = (size_t)M_ * D_;          // 2M floats
  const size_t SZ_MV = (size_t)M_ * H_ * DV_;    // 4M floats
  float* h    = ws;                               // [0,2M)  -> WT -> go_bf/h2_bf
  float* pq   = ws + SZ_MD;                       // [2M,4M)  -> proj rows -> QKd -> y1
  float* pk   = ws + 2 * SZ_MD;                   // [4M,6M)  -> proj rows -> kdtT
  float* pv   = ws + 3 * SZ_MD;                   // [6M,10M) -> proj rows -> S_store -> a1
  float* gate = ws + 3 * SZ_MD + SZ_MV;           // [10M,14M)
  float* qb   = ws + 3 * SZ_MD + 2 * SZ_MV;       // [14M,16M)
  float* kb   = ws + 4 * SZ_MD + 2 * SZ_MV;       // [16M,18M)
  float* vb   = ws + 5 * SZ_MD + 2 * SZ_MV;       // [18M,22M) in-place u -> Û
  float* Sst  = pv;
  float* y1   = pq;
  float* a1   = pv;
  float* wtb  = h;                                // transposed W for chunk_rec
  float* proj = pq;                               // merged q|k|v proj [M][4096]
  float* smalls = ws + 5 * SZ_MD + 3 * SZ_MV;     // 22M
  float* pa  = smalls;
  float* pb  = pa + (size_t)M_ * H_;
  float* gv  = pb + (size_t)M_ * H_;
  float* bv  = gv + (size_t)M_ * H_;
  float* gam = bv + (size_t)M_ * H_;
  __hip_bfloat16* h_bf  = (__hip_bfloat16*)vb;
  __hip_bfloat16* wb1   = (__hip_bfloat16*)kb;    // [4096][1024] bf16 = 8MB
  __hip_bfloat16* wb2   = (__hip_bfloat16*)vb;
  __hip_bfloat16* go_bf = (__hip_bfloat16*)h;
  __hip_bfloat16* h2_bf = (__hip_bfloat16*)h;
  __hip_bfloat16* a1b   = (__hip_bfloat16*)qb;

  const dim3 blk256(256);
  const dim3 g_tr1024_1024(1024 / 32, 1024 / 32);
  const dim3 g_tr1024_2048(2048 / 32, 1024 / 32);
  const dim3 g_tr2048_1024(1024 / 32, 2048 / 32);
  const dim3 g_tr1024_2816(2816 / 32, 1024 / 32);
  const dim3 g_tr2816_1024(1024 / 32, 2816 / 32);

  rmsnorm_k<<<dim3(M_), blk256, 0, stream>>>(x, n1w, h, h_bf, D_, 1e-6f);
  // merged q|k|v projection: Wqkv^T = [4096][1024] bf16 in wb1
  transpose_bf16_k<<<g_tr1024_1024, blk256, 0, stream>>>(Wq, wb1, D_, 1024);
  transpose_bf16_k<<<g_tr1024_1024, blk256, 0, stream>>>(Wk, wb1 + (size_t)1024 * 1024, D_, 1024);
  transpose_bf16_k<<<g_tr1024_2048, blk256, 0, stream>>>(Wv, wb1 + (size_t)2048 * 1024, D_, 2048);
  mfma_gemm_k<128, 128><<<dim3(4096 / 128, M_ / 128), blk256, 0, stream>>>(h_bf, wb1, nullptr, proj, M_, 4096, D_, 0);
  transpose_bf16_k<<<g_tr1024_2048, blk256, 0, stream>>>(Wg, wb1, D_, 2048);
  mfma_gemm_k<128, 64><<<dim3(2048 / 64, M_ / 128), blk256, 0, stream>>>(h_bf, wb1, nullptr, gate, M_, 2048, D_, 0);
  skinny_k<<<dim3(M_), blk256, 0, stream>>>(h, Wa, Wb, pa, pb, D_);
  conv_silu_k<<<dim3(M_), blk256, 0, stream>>>(proj, cq, qb, H_ * DK_, 4096, 0);
  conv_silu_k<<<dim3(M_), blk256, 0, stream>>>(proj, ck, kb, H_ * DK_, 4096, 1024);
  conv_silu_k<<<dim3(M_), blk256, 0, stream>>>(proj, cv, vb, H_ * DV_, 4096, 2048);
  beta_g_k<<<dim3((M_ * H_ + 255) / 256), blk256, 0, stream>>>(pa, pb, dtb, Alog, gv, bv, M_ * H_);
  l2norm_k<<<dim3(M_ * H_), dim3(64), 0, stream>>>(qb, 0.125f);
  l2norm_k<<<dim3(M_ * H_), dim3(64), 0, stream>>>(kb, 1.0f);
  chunk_prep_k<<<dim3(32 * NCH), blk256, 0, stream>>>(qb, kb, vb, gv, bv, pq, pk, gam, wtb);
  chunk_rec_k<<<dim3(256), blk256, 0, stream>>>(wtb, vb, pk, gam, Sst);
  chunk_o_k<<<dim3(32 * NCH), dim3(128), 0, stream>>>(qb, pq, vb, Sst, gam, gate, onw, go_bf);
  transpose_bf16_k<<<g_tr2048_1024, blk256, 0, stream>>>(Wo, wb2, H_ * DV_, 1024);
  mfma_gemm_k<64, 64><<<dim3(1024 / 64, M_ / 64), blk256, 0, stream>>>(go_bf, wb2, x, y1, M_, 1024, H_ * DV_, 1);
  rmsnorm_k<<<dim3(M_), blk256, 0, stream>>>(y1, n2w, nullptr, h2_bf, D_, 1e-6f);
  transpose_bf16_k<<<g_tr1024_2816, blk256, 0, stream>>>(W1, wb2, D_, FH_);
  mfma_gemm_k<128, 64><<<dim3(FH_ / 64, M_ / 128), blk256, 0, stream>>>(h2_bf, wb2, nullptr, a1, M_, FH_, D_, 0);
  transpose_bf16_k<<<g_tr1024_2816, blk256, 0, stream>>>(W3, wb2, D_, FH_);
  mfma_gemm_k<128, 64><<<dim3(FH_ / 64, M_ / 128), blk256, 0, stream>>>(h2_bf, wb2, a1, a1b, M_, FH_, D_, 2);
  transpose_bf16_k<<<g_tr2816_1024, blk256, 0, stream>>>(W2, wb2, FH_, 1024);
  mfma_gemm_k<64, 64><<<dim3(1024 / 64, M_ / 64), blk256, 0, stream>>>(a1b, wb2, y1, out, M_, 1024, FH_, 1);
}

// Round 15
// 515.207 us; speedup vs baseline: 1.0994x; 1.0835x over previous
//
#include <hip/hip_runtime.h>
#include <hip/hip_bf16.h>
#include <math.h>

// Problem constants
#define B_  2
#define T_  1024
#define D_  1024
#define H_  16
#define DK_ 64
#define DV_ 128
#define FH_ 2816
#define M_  (B_ * T_)   // 2048 tokens
#define C_  64          // chunk length
#define NCH (T_ / C_)   // 16 chunks

typedef __attribute__((ext_vector_type(8))) short bf16x8;
typedef __attribute__((ext_vector_type(4))) float f32x4;

// ---------------------------------------------------------------------------
// rmsnorm (used for the second norm only; first norm is fused below)
__global__ __launch_bounds__(256) void rmsnorm_k(
    const float* __restrict__ x, const float* __restrict__ w,
    float* __restrict__ outf, __hip_bfloat16* __restrict__ outb,
    int D, float eps) {
  const int row = blockIdx.x;
  const float* xr = x + (size_t)row * D;
  float ss = 0.f;
  for (int i = threadIdx.x; i < D; i += blockDim.x) { float v = xr[i]; ss += v * v; }
  for (int off = 32; off > 0; off >>= 1) ss += __shfl_xor(ss, off, 64);
  __shared__ float wsum[4];
  __shared__ float s_scale;
  const int lane = threadIdx.x & 63, wid = threadIdx.x >> 6;
  if (lane == 0) wsum[wid] = ss;
  __syncthreads();
  if (threadIdx.x == 0) {
    float tot = 0.f;
    const int nw = blockDim.x >> 6;
    for (int i = 0; i < nw; ++i) tot += wsum[i];
    s_scale = rsqrtf(tot / (float)D + eps);
  }
  __syncthreads();
  const float sc = s_scale;
  for (int i = threadIdx.x; i < D; i += blockDim.x) {
    const float v = xr[i] * sc * w[i];
    if (outf) outf[(size_t)row * D + i] = v;
    if (outb) outb[(size_t)row * D + i] = __float2bfloat16(v);
  }
}

// ---------------------------------------------------------------------------
// Round-14 fusion: rmsnorm1 + skinny (h@[Wa|Wb]) + beta_g in one kernel.
// Launch-count reduction (23 dispatches had ~100us of gaps vs ~460us kernel
// time). h row kept in LDS -> skinny skips its global h re-read; g/beta
// computed in-register, pa/pb buffers eliminated.
__global__ __launch_bounds__(256) void rms_skinny_k(
    const float* __restrict__ x, const float* __restrict__ n1w,
    const float* __restrict__ Wa, const float* __restrict__ Wb,
    const float* __restrict__ dtb, const float* __restrict__ Alog,
    float* __restrict__ hout, __hip_bfloat16* __restrict__ houtb,
    float* __restrict__ gv, float* __restrict__ bv) {
  __shared__ float hl[D_];
  __shared__ float red[8][32];
  __shared__ float wsum[4];
  __shared__ float s_scale;
  const int row = blockIdx.x;
  const int tid = threadIdx.x;
  const float* xr = x + (size_t)row * D_;
  float ss = 0.f;
  for (int i = tid; i < D_; i += 256) { float v = xr[i]; ss += v * v; }
  for (int off = 32; off > 0; off >>= 1) ss += __shfl_xor(ss, off, 64);
  const int lane = tid & 63, wid = tid >> 6;
  if (lane == 0) wsum[wid] = ss;
  __syncthreads();
  if (tid == 0) {
    float tot = wsum[0] + wsum[1] + wsum[2] + wsum[3];
    s_scale = rsqrtf(tot / (float)D_ + 1e-6f);
  }
  __syncthreads();
  const float sc = s_scale;
  for (int i = tid; i < D_; i += 256) {
    const float v = xr[i] * sc * n1w[i];
    hout[(size_t)row * D_ + i] = v;
    houtb[(size_t)row * D_ + i] = __float2bfloat16(v);
    hl[i] = v;
  }
  __syncthreads();
  // skinny: 8-way K-split
  const int col = tid & 31, sub = tid >> 5;
  const float* W = (col < 16) ? Wa : Wb;
  const int cc = col & 15;
  float s = 0.f;
  const int kk0 = sub * 128;
  for (int k = kk0; k < kk0 + 128; ++k) s += hl[k] * W[k * H_ + cc];
  red[sub][col] = s;
  __syncthreads();
  if (tid < 32) {
    float t = 0.f;
#pragma unroll
    for (int i = 0; i < 8; ++i) t += red[i][tid];
    if (tid < 16) {
      const float xx = t + dtb[tid];
      const float sp = (xx > 20.f) ? xx : log1pf(expf(xx));
      gv[(size_t)row * H_ + tid] = -expf(Alog[tid]) * sp;
    } else {
      bv[(size_t)row * H_ + tid - 16] = 1.f / (1.f + expf(-t));
    }
  }
}

// ---------------------------------------------------------------------------
// Multi-weight tiled transpose + fp32->bf16: up to 4 entries in ONE launch.
// Entry picked by tile-count prefix boundaries e1/e2/e3 (e3 == gridDim.x
// makes entry 3 unreachable when only 3 entries are used).
__global__ __launch_bounds__(256) void transpose_multi_k(
    const float* __restrict__ s0, const float* __restrict__ s1,
    const float* __restrict__ s2, const float* __restrict__ s3,
    __hip_bfloat16* __restrict__ d0, __hip_bfloat16* __restrict__ d1,
    __hip_bfloat16* __restrict__ d2, __hip_bfloat16* __restrict__ d3,
    int K0, int N0, int K1, int N1, int K2, int N2, int K3, int N3,
    int e1, int e2, int e3) {
  __shared__ float t[32][33];
  int tb = blockIdx.x;
  const float* W;
  __hip_bfloat16* Wt;
  int K, N;
  if (tb < e1)      { W = s0; Wt = d0; K = K0; N = N0; }
  else if (tb < e2) { W = s1; Wt = d1; K = K1; N = N1; tb -= e1; }
  else if (tb < e3) { W = s2; Wt = d2; K = K2; N = N2; tb -= e2; }
  else              { W = s3; Wt = d3; K = K3; N = N3; tb -= e3; }
  const int tpr = N >> 5;
  const int k0 = (tb / tpr) * 32, n0 = (tb % tpr) * 32;
  const int c = threadIdx.x & 31, r = threadIdx.x >> 5;  // r in 0..7
#pragma unroll
  for (int i = 0; i < 4; ++i)
    t[r + 8 * i][c] = W[(size_t)(k0 + r + 8 * i) * N + n0 + c];
  __syncthreads();
#pragma unroll
  for (int i = 0; i < 4; ++i)
    Wt[(size_t)(n0 + r + 8 * i) * K + k0 + c] = __float2bfloat16(t[c][r + 8 * i]);
}

// ---------------------------------------------------------------------------
__device__ __forceinline__ void gload_lds16(const void* g, void* l) {
  __builtin_amdgcn_global_load_lds(
      (const __attribute__((address_space(1))) void*)g,
      (__attribute__((address_space(3))) void*)l, 16, 0, 0);
}

// bf16 MFMA GEMM: C[M,N] = A[M,K] @ Bt[N,K]^T.  Tile BM x BN (64/128 each).
// BK=64 (two linear [BM][32] sub-tiles) + 2-phase double-buffered staging.
// Tile policy: 128x128 only where grid is an exact multiple of 256 (proj);
// elsewhere 128x64 / 64x64 for dispatch packing (round-12/13 lessons).
// mode 0: C = acc (fp32); mode 1: C = acc + res (fp32);
// mode 2: Cbf16 = silu(res) * acc   (fused SwiGLU epilogue)
template<int BM, int BN>
__global__ __launch_bounds__(256) void mfma_gemm_k(
    const __hip_bfloat16* __restrict__ A, const __hip_bfloat16* __restrict__ Bt,
    const float* __restrict__ res, void* __restrict__ Cout,
    int M, int N, int K, int mode) {
  __shared__ __hip_bfloat16 As[2][BM * 64];   // two [BM][32] sub-tiles each
  __shared__ __hip_bfloat16 Bs[2][BN * 64];
  constexpr int MF = BM / 32;        // a-frags per wave (4 or 2)
  constexpr int NF = BN / 32;        // b-frags per wave (4 or 2)
  const int tid = threadIdx.x;
  const int lane = tid & 63;
  const int wv = tid >> 6;
  const int wm = (wv >> 1) * (BM / 2), wn = (wv & 1) * (BN / 2);
  const int bm = blockIdx.y * BM, bn = blockIdx.x * BN;
  const int l15 = lane & 15, lq8 = (lane >> 4) * 8;
  const int ar = tid >> 2;
  const int ac = (tid & 3) * 8;
  const size_t Abase = (size_t)(bm + ar) * K + ac;
  const size_t Bbase = (size_t)(bn + ar) * K + ac;
  f32x4 acc[MF][NF];
#pragma unroll
  for (int i = 0; i < MF; ++i)
#pragma unroll
    for (int j = 0; j < NF; ++j) acc[i][j] = (f32x4){0.f, 0.f, 0.f, 0.f};

  // stage 64-wide k-slab [k0,k0+64) into buffer buf as two linear sub-tiles
  auto stage = [&](int buf, int k0) {
#pragma unroll
    for (int s = 0; s < 2; ++s) {
      const int kk = k0 + 32 * s;
      char* dA = (char*)&As[buf][s * BM * 32] + tid * 16;
      gload_lds16(A + Abase + kk, dA);
      if constexpr (BM == 128)
        gload_lds16(A + Abase + (size_t)64 * K + kk, dA + 4096);
      char* dB = (char*)&Bs[buf][s * BN * 32] + tid * 16;
      gload_lds16(Bt + Bbase + kk, dB);
      if constexpr (BN == 128)
        gload_lds16(Bt + Bbase + (size_t)64 * K + kk, dB + 4096);
    }
  };

  stage(0, 0);
  __syncthreads();                 // implicit vmcnt(0): buf0 ready
  int cur = 0;
#pragma unroll 2
  for (int k0 = 0; k0 < K; k0 += 64) {
    if (k0 + 64 < K) stage(cur ^ 1, k0 + 64);   // in flight during compute
#pragma unroll
    for (int s = 0; s < 2; ++s) {
      bf16x8 af[MF], bfr[NF];
#pragma unroll
      for (int i = 0; i < MF; ++i)
        af[i] = *(const bf16x8*)(&As[cur][s * BM * 32] + (wm + i * 16 + l15) * 32 + lq8);
#pragma unroll
      for (int j = 0; j < NF; ++j)
        bfr[j] = *(const bf16x8*)(&Bs[cur][s * BN * 32] + (wn + j * 16 + l15) * 32 + lq8);
#pragma unroll
      for (int i = 0; i < MF; ++i)
#pragma unroll
        for (int j = 0; j < NF; ++j)
          acc[i][j] = __builtin_amdgcn_mfma_f32_16x16x32_bf16(af[i], bfr[j], acc[i][j], 0, 0, 0);
    }
    __syncthreads();               // drains the k0+64 glds AFTER compute
    cur ^= 1;
  }
  const int r0 = (lane >> 4) * 4;
#pragma unroll
  for (int i = 0; i < MF; ++i) {
#pragma unroll
    for (int j = 0; j < NF; ++j) {
      const int row = bm + wm + i * 16 + r0;
      const int col = bn + wn + j * 16 + l15;
#pragma unroll
      for (int r = 0; r < 4; ++r) {
        const size_t idx = (size_t)(row + r) * N + col;
        const float a = acc[i][j][r];
        if (mode == 0) ((float*)Cout)[idx] = a;
        else if (mode == 1) ((float*)Cout)[idx] = a + res[idx];
        else {
          const float s = res[idx];
          ((__hip_bfloat16*)Cout)[idx] =
              __float2bfloat16(s * (1.f / (1.f + __expf(-s))) * a);
        }
      }
    }
  }
}

// ---------------------------------------------------------------------------
// Fused causal depthwise conv + silu for q|k|v from merged proj [M][4096].
__global__ __launch_bounds__(256) void conv_fused_k(
    const float* __restrict__ proj, const float* __restrict__ cq,
    const float* __restrict__ ck, const float* __restrict__ cv,
    float* __restrict__ qb, float* __restrict__ kb, float* __restrict__ vb) {
  const int bt = blockIdx.x;
  const int b = bt / T_, t = bt % T_;
  const float* s = proj + (size_t)b * T_ * 4096;
  const int tid = threadIdx.x;
  // segment 0: q (cols 0..1023 -> qb), 1: k (1024..2047 -> kb),
  // segment 2: v (2048..4095 -> vb)
#pragma unroll 1
  for (int seg = 0; seg < 3; ++seg) {
    const int C = (seg == 2) ? 2048 : 1024;
    const int off = (seg == 0) ? 0 : (seg == 1 ? 1024 : 2048);
    const float* w = (seg == 0) ? cq : (seg == 1 ? ck : cv);
    float* dst = (seg == 0) ? qb : (seg == 1 ? kb : vb);
    for (int c = tid; c < C; c += 256) {
      const float w0 = w[c * 4 + 0], w1 = w[c * 4 + 1],
                  w2 = w[c * 4 + 2], w3 = w[c * 4 + 3];
      float acc = s[(size_t)t * 4096 + off + c] * w3;
      if (t >= 1) acc += s[(size_t)(t - 1) * 4096 + off + c] * w2;
      if (t >= 2) acc += s[(size_t)(t - 2) * 4096 + off + c] * w1;
      if (t >= 3) acc += s[(size_t)(t - 3) * 4096 + off + c] * w0;
      dst[(size_t)bt * C + c] = acc * (1.f / (1.f + __expf(-acc)));
    }
  }
}

// ---------------------------------------------------------------------------
// Fused l2norm for q and k in one launch (grid 2*M_*H_).
__global__ __launch_bounds__(64) void l2norm2_k(float* __restrict__ q,
                                                float* __restrict__ k) {
  const size_t row = blockIdx.x;
  const size_t nq = (size_t)M_ * H_;
  float* p;
  float scale;
  if (row < nq) { p = q + row * 64; scale = 0.125f; }
  else          { p = k + (row - nq) * 64; scale = 1.0f; }
  const int lane = threadIdx.x;
  const float v = p[lane];
  float ss = v * v;
  for (int off = 32; off > 0; off >>= 1) ss += __shfl_xor(ss, off, 64);
  p[lane] = v * rsqrtf(ss + 1e-6f) * scale;
}

// ---------------------------------------------------------------------------
// Chunked gated delta rule, phase A. Barrier-free solve (round 8).
__global__ __launch_bounds__(256) void chunk_prep_k(
    const float* __restrict__ q, float* __restrict__ k, float* __restrict__ v,
    const float* __restrict__ g, const float* __restrict__ beta,
    float* __restrict__ qkd, float* __restrict__ kdt, float* __restrict__ gam,
    float* __restrict__ wt) {
  const int task = blockIdx.x;
  const int bh = task >> 4, n = task & (NCH - 1);
  const int b = bh >> 4, h = bh & 15;
  const int t0 = n * C_;
  const int tid = threadIdx.x;
  __shared__ float lk[C_][68];     // staged k rows
  __shared__ float Gs[C_][68];     // strict-lower β-folded Gram (zeros above)
  __shared__ float Xs[C_][100];    // 96-column RHS/solution panel
  __shared__ float Td[4][16][17];  // 16x16 diagonal-block inverses
  __shared__ float lb[C_], lgam[C_], lbeta[C_], lbg[C_];
  // stage k chunk
  {
    const int r = tid >> 2, cq = (tid & 3) * 16;
    const float* src = k + (((size_t)b * T_ + t0 + r) * H_ + h) * DK_ + cq;
#pragma unroll
    for (int i = 0; i < 4; ++i)
      *(float4*)&lk[r][cq + 4 * i] = ((const float4*)src)[i];
  }
  // g cumsum (wave 0), γ, β, βγ
  if (tid < 64) {
    const size_t gi = ((size_t)b * T_ + t0 + tid) * H_ + h;
    float xx = g[gi];
    const float bb = beta[gi];
    lbeta[tid] = bb;
#pragma unroll
    for (int off = 1; off < 64; off <<= 1) {
      float y = __shfl_up(xx, off, 64);
      if (tid >= off) xx += y;
    }
    lb[tid] = xx;
    const float gm = __expf(xx);
    lgam[tid] = gm;
    lbg[tid] = bb * gm;
  }
  __syncthreads();
  const int r4g = (tid >> 4) * 4;
  const int sl = tid & 15;
  // Gram: G = β-folded strict-lower K K^T decay; QKd = (Q K^T) decay
  {
    const float* qg = q + (((size_t)b * T_ + t0) * H_ + h) * DK_;
    float accA[4][4] = {};
    float accQ[4][4] = {};
    for (int d = 0; d < 64; d += 4) {
      float4 kt[4], ks[4], qt[4];
#pragma unroll
      for (int i = 0; i < 4; ++i) kt[i] = *(const float4*)&lk[r4g + i][d];
#pragma unroll
      for (int j = 0; j < 4; ++j) ks[j] = *(const float4*)&lk[sl + 16 * j][d];
#pragma unroll
      for (int i = 0; i < 4; ++i) qt[i] = *(const float4*)(qg + (size_t)(r4g + i) * (H_ * DK_) + d);
#pragma unroll
      for (int i = 0; i < 4; ++i)
#pragma unroll
        for (int j = 0; j < 4; ++j) {
          accA[i][j] += kt[i].x * ks[j].x + kt[i].y * ks[j].y + kt[i].z * ks[j].z + kt[i].w * ks[j].w;
          accQ[i][j] += qt[i].x * ks[j].x + qt[i].y * ks[j].y + qt[i].z * ks[j].z + qt[i].w * ks[j].w;
        }
    }
    float* qo = qkd + (size_t)task * 4096;
#pragma unroll
    for (int i = 0; i < 4; ++i)
#pragma unroll
      for (int j = 0; j < 4; ++j) {
        const int t = r4g + i, s = sl + 16 * j;
        const float dec = (s <= t) ? __expf(lb[t] - lb[s]) : 0.f;
        Gs[t][s] = (t > s) ? lbeta[t] * accA[i][j] * dec : 0.f;
        qo[t * 64 + s] = accQ[i][j] * dec;
      }
  }
  // kdtT[s][dk] = k[s][dk] * exp(bC - lb[s])  (coalesced rows, 1 exp/thread)
  {
    const int s = tid >> 2, dq = (tid & 3) * 16;
    const float e = __expf(lb[63] - lb[s]);
    float* dst = kdt + (size_t)task * 4096 + s * 64 + dq;
#pragma unroll
    for (int m = 0; m < 4; ++m) {
      float4 kv = *(const float4*)&lk[s][dq + 4 * m];
      kv.x *= e; kv.y *= e; kv.z *= e; kv.w *= e;
      *(float4*)(dst + 4 * m) = kv;
    }
  }
  if (tid < 64) gam[(size_t)task * 64 + tid] = lgam[tid];
  __syncthreads();
  // Td (threads 0..63: 4 blocks x 16 columns, registers only) + RHS0 load
  if (tid < 64) {
    const int blk = tid >> 4, cI = tid & 15;
    float Xc[16];
#pragma unroll
    for (int t = 0; t < 16; ++t) Xc[t] = (t == cI) ? 1.f : 0.f;
#pragma unroll
    for (int t = 1; t < 16; ++t) {
      float acc = 0.f;
#pragma unroll
      for (int s = 0; s < t; ++s)
        acc += Gs[blk * 16 + t][blk * 16 + s] * Xc[s];
      Xc[t] -= acc;
    }
#pragma unroll
    for (int t = 0; t < 16; ++t) Td[blk][t][cI] = Xc[t];
  } else {
    // RHS half 0: βV columns 0..95 (192 threads, 32 cells each)
    for (int idx = tid - 64; idx < 64 * 96; idx += 192) {
      const int t = idx / 96, c = idx % 96;
      Xs[t][c] = lbeta[t] * v[(((size_t)b * T_ + t0 + t) * H_ + h) * DV_ + c];
    }
  }
  __syncthreads();
  const int rt = tid & 15;          // row within block
  const int cg = tid >> 4;          // column group: cols cg*6 .. cg*6+5
#pragma unroll 1
  for (int half = 0; half < 2; ++half) {
    // 4-stage blocked sweep — BARRIER-FREE (quarter-wave column ownership;
    // same-wave LDS forwarding)
#pragma unroll
    for (int bi = 0; bi < 4; ++bi) {
      if (bi > 0) {
        float acc[6] = {0.f, 0.f, 0.f, 0.f, 0.f, 0.f};
        for (int kk = 0; kk < 16 * bi; ++kk) {
          const float gvv = Gs[16 * bi + rt][kk];
#pragma unroll
          for (int c = 0; c < 6; ++c) acc[c] += gvv * Xs[kk][cg * 6 + c];
        }
#pragma unroll
        for (int c = 0; c < 6; ++c) Xs[16 * bi + rt][cg * 6 + c] -= acc[c];
      }
      float y[6] = {0.f, 0.f, 0.f, 0.f, 0.f, 0.f};
#pragma unroll
      for (int s = 0; s < 16; ++s) {
        const float tv = Td[bi][rt][s];
#pragma unroll
        for (int c = 0; c < 6; ++c) y[c] += tv * Xs[16 * bi + s][cg * 6 + c];
      }
#pragma unroll
      for (int c = 0; c < 6; ++c) Xs[16 * bi + rt][cg * 6 + c] = y[c];
    }
    __syncthreads();   // solve complete -> all-thread writeback
    // writeback + next RHS
    if (half == 0) {
      for (int idx = tid; idx < 64 * 96; idx += 256) {
        const int t = idx / 96, c = idx % 96;
        v[(((size_t)b * T_ + t0 + t) * H_ + h) * DV_ + c] = Xs[t][c];
      }
      __syncthreads();   // writeback reads done before RHS overwrite
      // RHS half 1: cols 0..31 = βV cols 96..127; cols 32..95 = βγ·K cols 0..63
      for (int idx = tid; idx < 64 * 96; idx += 256) {
        const int t = idx / 96, c = idx % 96;
        if (c < 32)
          Xs[t][c] = lbeta[t] * v[(((size_t)b * T_ + t0 + t) * H_ + h) * DV_ + 96 + c];
        else
          Xs[t][c] = lbg[t] * lk[t][c - 32];
      }
      __syncthreads();   // RHS visible to solver quarter-waves
    } else {
      // v cols 96..127
      for (int idx = tid; idx < 64 * 32; idx += 256) {
        const int t = idx >> 5, cc = idx & 31;
        v[(((size_t)b * T_ + t0 + t) * H_ + h) * DV_ + 96 + cc] = Xs[t][cc];
      }
      // wt[task][dk][t] = Xs[t][32+dk]  (transposed W; coalesced per-thread rows)
      {
        const int dk = tid & 63, tg = tid >> 6;
        float buf[16];
#pragma unroll
        for (int j = 0; j < 16; ++j) buf[j] = Xs[16 * tg + j][32 + dk];
        float* dst = wt + (size_t)task * 4096 + dk * 64 + 16 * tg;
#pragma unroll
        for (int m = 0; m < 4; ++m)
          *(float4*)(dst + 4 * m) =
              make_float4(buf[4 * m], buf[4 * m + 1], buf[4 * m + 2], buf[4 * m + 3]);
      }
    }
  }
}

// ---------------------------------------------------------------------------
// Serial recurrence — round-9 256-thread version (best measured: 46.6us).
__global__ __launch_bounds__(256) void chunk_rec_k(
    const float* __restrict__ WT, float* __restrict__ u,
    const float* __restrict__ kdtT, const float* __restrict__ gam,
    float* __restrict__ Sst) {
  const int bh = blockIdx.x & 31, cg = blockIdx.x >> 5;   // XCD swizzle kept
  const int b = bh >> 4, h = bh & 15;
  const int c0 = cg * 16;
  const int tid = threadIdx.x;
  const int w = tid >> 6;             // wave 0..3
  const int lane = tid & 63;
  const int L15 = lane & 15;
  const int t4 = L15 * 4;             // 4 rows (tokens in mm1 / dk in mm2)
  const int c = w * 4 + (lane >> 4);  // owned column (0..15)
  const int iot = tid >> 2;           // I/O ownership: row 0..63
  const int ioq = (tid & 3) * 4;      // I/O col quad base

  __shared__ float Wt[2][64 * 64];    // [buf][dk*64+token]  (linear, glds dest)
  __shared__ float Kt[2][64 * 64];    // [buf][s*64+dk]
  __shared__ float SsT[16][68];       // S^T [col][dk]
  __shared__ float UbT[16][68];       // U^T [col][s]
  __shared__ float Ub0[64][17];       // staged u [t][col]

  float Sr[4];
#pragma unroll
  for (int i = 0; i < 4; ++i) Sr[i] = 0.f;
#pragma unroll
  for (int i = 0; i < 4; ++i) SsT[c][t4 + i] = 0.f;

  // prologue: glds chunk 0 into buffer 0 (each wave stages its row quarter)
  {
    const float* sW = WT + (size_t)(bh * NCH) * 4096 + w * 1024 + lane * 4;
    const float* sK = kdtT + (size_t)(bh * NCH) * 4096 + w * 1024 + lane * 4;
    char* lW = (char*)&Wt[0][w * 1024] + lane * 16;
    char* lK = (char*)&Kt[0][w * 1024] + lane * 16;
#pragma unroll
    for (int i = 0; i < 4; ++i) {
      gload_lds16(sW + i * 256, lW + i * 1024);
      gload_lds16(sK + i * 256, lK + i * 1024);
    }
  }
  __syncthreads();

#pragma unroll 1
  for (int n = 0; n < NCH; ++n) {
    const int cur = n & 1, nx = cur ^ 1;
    const int task = bh * NCH + n;
    const int t0 = n * C_;
    const int n1 = (n + 1 < NCH) ? n + 1 : NCH - 1;   // clamped (no branch BB)
    const int task1 = bh * NCH + n1;
    const float gC = gam[(size_t)task * 64 + 63];

    // A1: issue coalesced u load FIRST (its wait then leaves glds in flight)
    const float4 uv = *(const float4*)(
        u + (((size_t)b * T_ + t0 + iot) * H_ + h) * DV_ + c0 + ioq);
    // A2: issue next-chunk glds staging (drained at bar1; hidden under mm1)
    {
      const float* sW = WT + (size_t)task1 * 4096 + w * 1024 + lane * 4;
      const float* sK = kdtT + (size_t)task1 * 4096 + w * 1024 + lane * 4;
      char* lW = (char*)&Wt[nx][w * 1024] + lane * 16;
      char* lK = (char*)&Kt[nx][w * 1024] + lane * 16;
#pragma unroll
      for (int i = 0; i < 4; ++i) {
        gload_lds16(sW + i * 256, lW + i * 1024);
        gload_lds16(sK + i * 256, lK + i * 1024);
      }
    }
    __builtin_amdgcn_sched_barrier(0);
    // A3: Sst writeback (pre-chunk state, coalesced; reads SsT cross-wave,
    //     ordered by prior bar2 / init)
    {
      float4 sv;
      sv.x = SsT[ioq + 0][iot]; sv.y = SsT[ioq + 1][iot];
      sv.z = SsT[ioq + 2][iot]; sv.w = SsT[ioq + 3][iot];
      *(float4*)(Sst + (size_t)task * 8192 + iot * 128 + c0 + ioq) = sv;
    }
    // A4: mm1: acc[i] = sum_k W[t4+i][k] * S[k][c]
    float4 srow[16];
#pragma unroll
    for (int g = 0; g < 16; ++g) srow[g] = *(const float4*)&SsT[c][4 * g];
    float acc[4] = {0.f, 0.f, 0.f, 0.f};
#pragma unroll
    for (int g = 0; g < 16; ++g) {
      const float sj[4] = {srow[g].x, srow[g].y, srow[g].z, srow[g].w};
#pragma unroll
      for (int j = 0; j < 4; ++j) {
        const float4 wv = *(const float4*)&Wt[cur][(4 * g + j) * 64 + t4];
        acc[0] += wv.x * sj[j]; acc[1] += wv.y * sj[j];
        acc[2] += wv.z * sj[j]; acc[3] += wv.w * sj[j];
      }
    }
    // A5: commit staged u -> Ub0 (vmcnt wait covered by mm1)
    Ub0[iot][ioq + 0] = uv.x; Ub0[iot][ioq + 1] = uv.y;
    Ub0[iot][ioq + 2] = uv.z; Ub0[iot][ioq + 3] = uv.w;
    __syncthreads();  // bar1: Ub0 visible; glds for [nx] drained

    // B1: U-form (reads Ub0 cross-wave; writes UbT same-wave rows)
#pragma unroll
    for (int i = 0; i < 4; ++i)
      UbT[c][t4 + i] = Ub0[t4 + i][c] - acc[i];
    // B2: mm2: acc2[i] = sum_s K̂[s][t4+i] * U[s][c]  (same-wave UbT row)
    float4 urow[16];
#pragma unroll
    for (int g = 0; g < 16; ++g) urow[g] = *(const float4*)&UbT[c][4 * g];
    float ac2[4] = {0.f, 0.f, 0.f, 0.f};
#pragma unroll
    for (int g = 0; g < 16; ++g) {
      const float uj[4] = {urow[g].x, urow[g].y, urow[g].z, urow[g].w};
#pragma unroll
      for (int j = 0; j < 4; ++j) {
        const float4 kv = *(const float4*)&Kt[cur][(4 * g + j) * 64 + t4];
        ac2[0] += kv.x * uj[j]; ac2[1] += kv.y * uj[j];
        ac2[2] += kv.z * uj[j]; ac2[3] += kv.w * uj[j];
      }
    }
    // B3: state update + SsT write (same-wave rows)
#pragma unroll
    for (int i = 0; i < 4; ++i) {
      Sr[i] = gC * Sr[i] + ac2[i];
      SsT[c][t4 + i] = Sr[i];
    }
    __syncthreads();  // bar2: UbT/SsT complete

    // C: coalesced u writeback from UbT (cross-wave, ordered by bar2)
    {
      float4 ov;
      ov.x = UbT[ioq + 0][iot]; ov.y = UbT[ioq + 1][iot];
      ov.z = UbT[ioq + 2][iot]; ov.w = UbT[ioq + 3][iot];
      *(float4*)(u + (((size_t)b * T_ + t0 + iot) * H_ + h) * DV_ + c0 + ioq) = ov;
    }
  }
}

// ---------------------------------------------------------------------------
// Parallel O with fused gatenorm (unchanged).
__global__ __launch_bounds__(128) void chunk_o_k(
    const float* __restrict__ q, const float* __restrict__ qkd,
    const float* __restrict__ ub, const float* __restrict__ Sst,
    const float* __restrict__ gam, const float* __restrict__ gate,
    const float* __restrict__ onw, __hip_bfloat16* __restrict__ go) {
  const int task = blockIdx.x;
  const int bh = task >> 4, n = task & 15;
  const int b = bh >> 4, h = bh & 15;
  const int t0 = n * C_;
  const int tid = threadIdx.x;
  const int rowg = tid >> 4, colg = tid & 15;
  const int r8 = rowg * 8, c4 = colg * 4;
  __shared__ float At[64][68];
  __shared__ float Bs[64][132];
  __shared__ float lgam[64];
  if (tid < 64) lgam[tid] = gam[(size_t)task * 64 + tid];
  __syncthreads();
  const int t2 = tid >> 1, dh = (tid & 1) * 32;
  {
    const float* src = q + (((size_t)b * T_ + t0 + t2) * H_ + h) * DK_ + dh;
    const float sc = lgam[t2];
#pragma unroll
    for (int i = 0; i < 8; ++i) {
      const float4 v = ((const float4*)src)[i];
      At[dh + 4 * i + 0][t2] = v.x * sc; At[dh + 4 * i + 1][t2] = v.y * sc;
      At[dh + 4 * i + 2][t2] = v.z * sc; At[dh + 4 * i + 3][t2] = v.w * sc;
    }
  }
  {
    const float* src = Sst + (size_t)task * 8192 + t2 * 128 + (tid & 1) * 64;
    float* dst = &Bs[t2][(tid & 1) * 64];
#pragma unroll
    for (int i = 0; i < 16; ++i) ((float4*)dst)[i] = ((const float4*)src)[i];
  }
  __syncthreads();
  float acc[8][8];
#pragma unroll
  for (int i = 0; i < 8; ++i)
#pragma unroll
    for (int c = 0; c < 8; ++c) acc[i][c] = 0.f;
#pragma unroll 1
  for (int ph = 0; ph < 2; ++ph) {
    for (int kb = 0; kb < 64; kb += 4) {
#pragma unroll
      for (int j = 0; j < 4; ++j) {
        const float4 alo = *(const float4*)&At[kb + j][r8];
        const float4 ahi = *(const float4*)&At[kb + j][r8 + 4];
        const float4 blo = *(const float4*)&Bs[kb + j][c4];
        const float4 bhi = *(const float4*)&Bs[kb + j][c4 + 64];
        const float av[8] = {alo.x, alo.y, alo.z, alo.w, ahi.x, ahi.y, ahi.z, ahi.w};
        const float bv[8] = {blo.x, blo.y, blo.z, blo.w, bhi.x, bhi.y, bhi.z, bhi.w};
#pragma unroll
        for (int i = 0; i < 8; ++i)
#pragma unroll
          for (int c = 0; c < 8; ++c) acc[i][c] += av[i] * bv[c];
      }
    }
    if (ph == 0) {
      __syncthreads();
      {
        const float* src = qkd + (size_t)task * 4096 + t2 * 64 + dh;
#pragma unroll
        for (int i = 0; i < 8; ++i) {
          const float4 v = ((const float4*)src)[i];
          At[dh + 4 * i + 0][t2] = v.x; At[dh + 4 * i + 1][t2] = v.y;
          At[dh + 4 * i + 2][t2] = v.z; At[dh + 4 * i + 3][t2] = v.w;
        }
      }
      {
        const float* src = ub + (((size_t)b * T_ + t0 + t2) * H_ + h) * DV_ + (tid & 1) * 64;
        float* dst = &Bs[t2][(tid & 1) * 64];
#pragma unroll
        for (int i = 0; i < 16; ++i) ((float4*)dst)[i] = ((const float4*)src)[i];
      }
      __syncthreads();
    }
  }
#pragma unroll
  for (int i = 0; i < 8; ++i) {
    float pr = 0.f;
#pragma unroll
    for (int c = 0; c < 8; ++c) pr += acc[i][c] * acc[i][c];
    pr += __shfl_xor(pr, 1, 64);
    pr += __shfl_xor(pr, 2, 64);
    pr += __shfl_xor(pr, 4, 64);
    pr += __shfl_xor(pr, 8, 64);
    const float rms = rsqrtf(pr / (float)DV_ + 1e-5f);
    const size_t rb = (((size_t)b * T_ + t0 + r8 + i) * H_ + h) * DV_;
    const float4 glo = *(const float4*)(gate + rb + c4);
    const float4 ghi = *(const float4*)(gate + rb + c4 + 64);
    const float gv[8] = {glo.x, glo.y, glo.z, glo.w, ghi.x, ghi.y, ghi.z, ghi.w};
    unsigned short outv[8];
#pragma unroll
    for (int c = 0; c < 8; ++c) {
      const int col = (c < 4) ? c4 + c : c4 + 60 + c;
      const float gg = gv[c];
      const float val = acc[i][c] * rms * onw[col] * gg * (1.f / (1.f + __expf(-gg)));
      const __hip_bfloat16 bfv = __float2bfloat16(val);
      outv[c] = *(const unsigned short*)&bfv;
    }
    *(ushort4*)((unsigned short*)go + rb + c4) =
        make_ushort4(outv[0], outv[1], outv[2], outv[3]);
    *(ushort4*)((unsigned short*)go + rb + c4 + 64) =
        make_ushort4(outv[4], outv[5], outv[6], outv[7]);
  }
}

// ---------------------------------------------------------------------------
extern "C" void kernel_launch(void* const* d_in, const int* in_sizes, int n_in,
                              void* d_out, int out_size, void* d_ws, size_t ws_size,
                              hipStream_t stream) {
  const float* x    = (const float*)d_in[0];
  const float* n1w  = (const float*)d_in[1];
  const float* n2w  = (const float*)d_in[2];
  const float* Wq   = (const float*)d_in[3];
  const float* Wk   = (const float*)d_in[4];
  const float* Wv   = (const float*)d_in[5];
  const float* cq   = (const float*)d_in[6];
  const float* ck   = (const float*)d_in[7];
  const float* cv   = (const float*)d_in[8];
  const float* Wa   = (const float*)d_in[9];
  const float* Wb   = (const float*)d_in[10];
  const float* dtb  = (const float*)d_in[11];
  const float* Alog = (const float*)d_in[12];
  const float* Wg   = (const float*)d_in[13];
  const float* onw  = (const float*)d_in[14];
  const float* Wo   = (const float*)d_in[15];
  const float* W1   = (const float*)d_in[16];
  const float* W3   = (const float*)d_in[17];
  const float* W2   = (const float*)d_in[18];
  float* out = (float*)d_out;
  float* ws  = (float*)d_ws;

  const size_t SZ_MD = (size_t)M_ * D_;          // 2M floats
  const size_t SZ_MV = (size_t)M_ * H_ * DV_;    // 4M floats
  float* h    = ws;                               // [0,2M)  -> WT -> go_bf/h2_bf
  float* pq   = ws + SZ_MD;                       // [2M,4M)  -> proj rows -> QKd -> y1
  float* pk   = ws + 2 * SZ_MD;                   // [4M,6M)  -> proj rows -> kdtT
  float* pv   = ws + 3 * SZ_MD;                   // [6M,10M) -> proj rows -> S_store -> a1
  float* gate = ws + 3 * SZ_MD + SZ_MV;           // [10M,14M)
  float* qb   = ws + 3 * SZ_MD + 2 * SZ_MV;       // [14M,16M)  (also Wg^T early)
  float* kb   = ws + 4 * SZ_MD + 2 * SZ_MV;       // [16M,18M)  (also Wqkv^T early)
  float* vb   = ws + 5 * SZ_MD + 2 * SZ_MV;       // [18M,22M) h_bf -> u -> Wo/W1/W3^T
  float* Sst  = pv;
  float* y1   = pq;
  float* a1   = pv;
  float* wtb  = h;                                // transposed W for chunk_rec
  float* proj = pq;                               // merged q|k|v proj [M][4096]
  float* smalls = ws + 5 * SZ_MD + 3 * SZ_MV;     // 22M
  float* gv  = smalls;
  float* bv  = gv + (size_t)M_ * H_;
  float* gam = bv + (size_t)M_ * H_;
  __hip_bfloat16* h_bf  = (__hip_bfloat16*)vb;
  __hip_bfloat16* wb1   = (__hip_bfloat16*)kb;    // Wqkv^T [4096][1024] = 8MB
  __hip_bfloat16* wgt   = (__hip_bfloat16*)qb;    // Wg^T   [2048][1024] = 4MB
  __hip_bfloat16* wb2   = (__hip_bfloat16*)vb;    // Wo^T|W1^T|W3^T (batch B)
  __hip_bfloat16* go_bf = (__hip_bfloat16*)h;
  __hip_bfloat16* h2_bf = (__hip_bfloat16*)h;
  __hip_bfloat16* a1b   = (__hip_bfloat16*)qb;

  const dim3 blk256(256);

  // 1) fused rmsnorm1 + skinny + beta_g
  rms_skinny_k<<<dim3(M_), blk256, 0, stream>>>(x, n1w, Wa, Wb, dtb, Alog, h, h_bf, gv, bv);
  // 2) batched transposes A: Wq|Wk|Wv -> wb1, Wg -> wgt (qb region, free now)
  transpose_multi_k<<<dim3(6144), blk256, 0, stream>>>(
      Wq, Wk, Wv, Wg,
      wb1, wb1 + (size_t)1024 * 1024, wb1 + (size_t)2048 * 1024, wgt,
      1024, 1024, 1024, 1024, 1024, 2048, 1024, 2048,
      1024, 2048, 4096);
  // 3) merged q|k|v projection (128^2: 512 blocks = exactly 2/CU)
  mfma_gemm_k<128, 128><<<dim3(4096 / 128, M_ / 128), blk256, 0, stream>>>(h_bf, wb1, nullptr, proj, M_, 4096, D_, 0);
  // 4) gate projection (reads Wg^T from qb region BEFORE conv overwrites qb)
  mfma_gemm_k<128, 64><<<dim3(2048 / 64, M_ / 128), blk256, 0, stream>>>(h_bf, wgt, nullptr, gate, M_, 2048, D_, 0);
  // 5) fused conv+silu for q|k|v
  conv_fused_k<<<dim3(M_), blk256, 0, stream>>>(proj, cq, ck, cv, qb, kb, vb);
  // 6) fused l2norm (q then k)
  l2norm2_k<<<dim3(2 * M_ * H_), dim3(64), 0, stream>>>(qb, kb);
  // 7-9) chunked delta rule
  chunk_prep_k<<<dim3(32 * NCH), blk256, 0, stream>>>(qb, kb, vb, gv, bv, pq, pk, gam, wtb);
  chunk_rec_k<<<dim3(256), blk256, 0, stream>>>(wtb, vb, pk, gam, Sst);
  chunk_o_k<<<dim3(32 * NCH), dim3(128), 0, stream>>>(qb, pq, vb, Sst, gam, gate, onw, go_bf);
  // 10) batched transposes B: Wo|W1|W3 -> wb2 (vb region free after chunk_o)
  transpose_multi_k<<<dim3(7680), blk256, 0, stream>>>(
      Wo, W1, W3, Wo,
      wb2, wb2 + (size_t)2048 * 1024, wb2 + (size_t)4864 * 1024, wb2,
      2048, 1024, 1024, 2816, 1024, 2816, 32, 32,
      2048, 4864, 7680);
  // 11) residual-1 output projection
  mfma_gemm_k<64, 64><<<dim3(1024 / 64, M_ / 64), blk256, 0, stream>>>(go_bf, wb2, x, y1, M_, 1024, H_ * DV_, 1);
  // 12) rmsnorm2
  rmsnorm_k<<<dim3(M_), blk256, 0, stream>>>(y1, n2w, nullptr, h2_bf, D_, 1e-6f);
  // 13) W1 GEMM (a1 = h2 @ W1)
  mfma_gemm_k<128, 64><<<dim3(FH_ / 64, M_ / 128), blk256, 0, stream>>>(
      h2_bf, wb2 + (size_t)2048 * 1024, nullptr, a1, M_, FH_, D_, 0);
  // 14) W3 GEMM with fused SwiGLU epilogue (a1b = silu(a1) * (h2 @ W3))
  mfma_gemm_k<128, 64><<<dim3(FH_ / 64, M_ / 128), blk256, 0, stream>>>(
      h2_bf, wb2 + (size_t)4864 * 1024, a1, a1b, M_, FH_, D_, 2);
  // 15) W2 transpose (overwrites Wo^T region; Wo GEMM already done)
  transpose_multi_k<<<dim3(2816), blk256, 0, stream>>>(
      W2, W2, W2, W2, wb2, wb2, wb2, wb2,
      2816, 1024, 2816, 1024, 2816, 1024, 2816, 1024,
      2816, 2816, 2816);
  // 16) W2 GEMM + residual-2
  mfma_gemm_k<64, 64><<<dim3(1024 / 64, M_ / 64), blk256, 0, stream>>>(a1b, wb2, y1, out, M_, 1024, FH_, 1);
}